// Round 4
// baseline (1756.276 us; speedup 1.0000x reference)
//
#include <hip/hip_runtime.h>
#include <math.h>

// ---------------- problem constants ----------------
#define BN_  4
#define TT   24
#define NN   4096
#define TO   12
#define MM   128
#define LL   (TO*MM)          // 1536
#define BL   (BN_*LL)         // 6144
#define DM   512
#define NH   8
#define DH   64
#define MLPD 1024
#define NC   30

// output layout (floats): logits | contrastive | features
#define OUT_LOGITS 0
#define OUT_CONTR  (BN_*NC)                 // 120
#define OUT_FEATS  (OUT_CONTR + BL*DM)      // 120 + 3145728

// weight-split region offsets (in shorts)
#define NWQ   3145728   // 4*1536*512
#define NWO   1048576   // 4*512*512
#define NWF1  2097152   // 4*1024*512
#define NWF2  2097152   // 4*512*1024
#define WQOFF   0
#define WOOFF   (NWQ)                 // 3145728
#define WF1OFF  (NWQ+NWO)             // 4194304
#define WF2OFF  (NWQ+NWO+NWF1)        // 6291456
#define WTOT    (NWQ+NWO+NWF1+NWF2)   // 8388608

typedef __attribute__((ext_vector_type(8))) short s16x8;
typedef __attribute__((ext_vector_type(4))) float f32x4;
#define MFMA(a,b,c) __builtin_amdgcn_mfma_f32_16x16x32_bf16(a,b,c,0,0,0)

// split fp32 -> bf16 hi (truncate) + bf16 lo (truncated residual); a ~= hi + lo
__device__ __forceinline__ void split_bf16(float a, short &h, short &l) {
  unsigned u = __float_as_uint(a);
  h = (short)(u >> 16);
  float ah = __uint_as_float(u & 0xffff0000u);
  float al = a - ah;
  l = (short)(__float_as_uint(al) >> 16);
}

// exact (non-FMA-contracted) squared distance, matching XLA's mul+add order
__device__ __forceinline__ float d2_3(float ax, float ay, float az,
                                      float bx, float by, float bz) {
#pragma clang fp contract(off)
  float dx = ax - bx, dy = ay - by, dz = az - bz;
  float dx2 = dx * dx, dy2 = dy * dy, dz2 = dz * dz;
  return (dx2 + dy2) + dz2;
}

__device__ __forceinline__ float gelu_f(float v) {
  return 0.5f * v * (1.0f + erff(v * 0.70710678118654752440f));
}

// ---------------- one-time weight split ----------------
__global__ __launch_bounds__(256) void splitw_kernel(
    const float* __restrict__ qkv_w, const float* __restrict__ out_w,
    const float* __restrict__ ff1_w, const float* __restrict__ ff2_w,
    short* __restrict__ wh, short* __restrict__ wl) {
  int i = blockIdx.x * 256 + threadIdx.x;
  const float* src; int off;
  if (i < WOOFF)        { src = qkv_w; off = i; }
  else if (i < WF1OFF)  { src = out_w; off = i - WOOFF; }
  else if (i < WF2OFF)  { src = ff1_w; off = i - WF1OFF; }
  else                  { src = ff2_w; off = i - WF2OFF; }
  float v = src[off];
  short h, l; split_bf16(v, h, l);
  wh[i] = h; wl[i] = l;
}

// ---------------- FPS v2: one block per (b, ti), 1 barrier/iter ----------------
__global__ __launch_bounds__(256) void fps_kernel(const float* __restrict__ xyzs,
                                                  float* __restrict__ anchor) {
  __shared__ float sx[NN], sy[NN], sz[NN];
  __shared__ unsigned long long skey[2][4];
  int blk = blockIdx.x;
  int b = blk / TO, ti = blk - b * TO;
  const float* src = xyzs + ((size_t)(b * TT + 2 * ti)) * NN * 3;
  int tid = threadIdx.x;
  float dist[16], px[16], py[16], pz[16];
#pragma unroll
  for (int s = 0; s < 16; ++s) {
    int p = tid + s * 256;
    px[s] = src[p * 3 + 0]; py[s] = src[p * 3 + 1]; pz[s] = src[p * 3 + 2];
    sx[p] = px[s]; sy[p] = py[s]; sz[p] = pz[s];
    dist[s] = 1e10f;
  }
  __syncthreads();
  float lx = sx[0], ly = sy[0], lz = sz[0];
  float* aout = anchor + (size_t)blk * MM * 3;
  if (tid == 0) { aout[0] = lx; aout[1] = ly; aout[2] = lz; }
  for (int j = 1; j < MM; ++j) {
    unsigned long long best = 0;
#pragma unroll
    for (int s = 0; s < 16; ++s) {
      float d2 = d2_3(px[s], py[s], pz[s], lx, ly, lz);
      float dn = fminf(dist[s], d2);
      dist[s] = dn;
      // key: dist bits (fp32, >=0 so monotone) << 12 | (4095 - idx); max-key = argmax with first-index ties
      unsigned long long key = ((unsigned long long)__float_as_uint(dn) << 12)
                               | (unsigned)(4095 - (tid + s * 256));
      best = key > best ? key : best;
    }
#pragma unroll
    for (int m = 1; m < 64; m <<= 1) {
      unsigned long long o = __shfl_xor(best, m, 64);
      best = o > best ? o : best;
    }
    if ((tid & 63) == 0) skey[j & 1][tid >> 6] = best;
    __syncthreads();
    unsigned long long b0 = skey[j & 1][0], b1 = skey[j & 1][1];
    unsigned long long b2 = skey[j & 1][2], b3 = skey[j & 1][3];
    unsigned long long bb = b0 > b1 ? b0 : b1;
    unsigned long long cc = b2 > b3 ? b2 : b3;
    bb = bb > cc ? bb : cc;
    int bi = 4095 - (int)(bb & 0xFFFull);
    lx = sx[bi]; ly = sy[bi]; lz = sz[bi];
    if (tid == 0) { aout[j * 3 + 0] = lx; aout[j * 3 + 1] = ly; aout[j * 3 + 2] = lz; }
  }
}

// ---------------- ball query + p4dconv + max-pool: one wave per (b,ti,m) ----------------
__global__ __launch_bounds__(64) void ballconv_kernel(
    const float* __restrict__ xyzs, const float* __restrict__ oldf,
    const float* __restrict__ anchor,
    const float* __restrict__ wdw, const float* __restrict__ wfw,
    float* __restrict__ dout) {
  __shared__ int   sidx[32];
  __shared__ float sdisp[32][4];
  __shared__ float sfeat[32][2];
  int blk = blockIdx.x;
  int b = blk / (TO * MM);
  int rem = blk - b * (TO * MM);
  int ti = rem / MM;
  int lane = threadIdx.x;
  const float* ap = anchor + (size_t)blk * 3;
  float ax = ap[0], ay = ap[1], az = ap[2];
  int d0 = lane * 8;
  float4 wd[8]; float2 wf[8];
#pragma unroll
  for (int jd = 0; jd < 8; ++jd) {
    wd[jd] = *(const float4*)(wdw + (d0 + jd) * 4);
    wf[jd] = *(const float2*)(wfw + (d0 + jd) * 2);
  }
  float fmx[8];
#pragma unroll
  for (int jd = 0; jd < 8; ++jd) fmx[jd] = -INFINITY;

  for (int o = -1; o <= 1; ++o) {
    int tp = 1 + 2 * ti + o;
    int orig = (tp == 0) ? 0 : tp - 1;
    const float* nx = xyzs + ((size_t)(b * TT + orig)) * NN * 3;
    const float* nf = oldf + ((size_t)(b * TT + orig)) * 2 * NN;
    int cnt = 0;
    for (int base = 0; base < NN && cnt < 32; base += 64) {
      int p = base + lane;
      float d2 = d2_3(ax, ay, az, nx[p * 3], nx[p * 3 + 1], nx[p * 3 + 2]);
      bool in = d2 < 0.09f;
      unsigned long long mask = __ballot(in);
      int pos = __popcll(mask & ((1ull << lane) - 1ull));
      if (in && (cnt + pos) < 32) sidx[cnt + pos] = p;
      cnt += __popcll(mask);
    }
    __syncthreads();
    int used = cnt < 32 ? cnt : 32;
    if (lane < 32 && lane >= used) sidx[lane] = (used > 0) ? sidx[0] : 0;
    __syncthreads();
    if (lane < 32) {
      int p = sidx[lane];
      sdisp[lane][0] = nx[p * 3 + 0] - ax;
      sdisp[lane][1] = nx[p * 3 + 1] - ay;
      sdisp[lane][2] = nx[p * 3 + 2] - az;
      sdisp[lane][3] = (float)o;
      sfeat[lane][0] = nf[p];
      sfeat[lane][1] = nf[NN + p];
    }
    __syncthreads();
    for (int k = 0; k < 32; ++k) {
      float p0 = sdisp[k][0], p1 = sdisp[k][1], p2 = sdisp[k][2], p3 = sdisp[k][3];
      float f0 = sfeat[k][0], f1 = sfeat[k][1];
#pragma unroll
      for (int jd = 0; jd < 8; ++jd) {
        float de = wd[jd].x * p0 + wd[jd].y * p1 + wd[jd].z * p2 + wd[jd].w * p3;
        float fe = wf[jd].x * f0 + wf[jd].y * f1;
        fmx[jd] = fmaxf(fmx[jd], fe * de);
      }
    }
    __syncthreads();
  }
  float* fout = dout + OUT_FEATS + (size_t)blk * DM + d0;
#pragma unroll
  for (int jd = 0; jd < 8; jd += 4)
    *(float4*)(fout + jd) = make_float4(fmx[jd], fmx[jd + 1], fmx[jd + 2], fmx[jd + 3]);
}

// ---------------- pos/contrastive embed + x = relu(pos + features) ----------------
__global__ __launch_bounds__(256) void posx_kernel(
    const float* __restrict__ anchor,
    const float* __restrict__ pw, const float* __restrict__ pb,
    const float* __restrict__ cw, const float* __restrict__ cb,
    float* __restrict__ dout, float* __restrict__ x) {
  int idx = blockIdx.x * 256 + threadIdx.x;
  int bl = idx >> 9, d = idx & 511;
  int ti = (bl % LL) / MM;
  const float* ap = anchor + (size_t)bl * 3;
  float c0 = ap[0], c1 = ap[1], c2 = ap[2], c3 = (float)(ti + 1);
  float4 pwv = *(const float4*)(pw + d * 4);
  float4 cwv = *(const float4*)(cw + d * 4);
  float pos = pwv.x * c0 + pwv.y * c1 + pwv.z * c2 + pwv.w * c3 + pb[d];
  float con = cwv.x * c0 + cwv.y * c1 + cwv.z * c2 + cwv.w * c3 + cb[d];
  dout[OUT_CONTR + (size_t)idx] = con;
  float v = pos + dout[OUT_FEATS + (size_t)idx];
  x[idx] = v > 0.0f ? v : 0.0f;
}

// ---------------- LayerNorm -> split bf16 hi/lo: one wave per row ----------------
__global__ __launch_bounds__(64) void ln_split_kernel(
    const float* __restrict__ x, const float* __restrict__ gs,
    const float* __restrict__ gb, short* __restrict__ oh, short* __restrict__ ol) {
  int row = blockIdx.x, lane = threadIdx.x;
  const float* xr = x + (size_t)row * DM + lane * 8;
  float4 v0 = *(const float4*)xr;
  float4 v1 = *(const float4*)(xr + 4);
  float v[8] = {v0.x, v0.y, v0.z, v0.w, v1.x, v1.y, v1.z, v1.w};
  float s = 0.f;
#pragma unroll
  for (int j = 0; j < 8; ++j) s += v[j];
  for (int m = 1; m < 64; m <<= 1) s += __shfl_xor(s, m, 64);
  float mu = s * (1.0f / DM);
  float d[8], ss = 0.f;
#pragma unroll
  for (int j = 0; j < 8; ++j) { d[j] = v[j] - mu; ss += d[j] * d[j]; }
  for (int m = 1; m < 64; m <<= 1) ss += __shfl_xor(ss, m, 64);
  float rs = 1.0f / sqrtf(ss * (1.0f / DM) + 1e-5f);
  const float* gsr = gs + lane * 8;
  const float* gbr = gb + lane * 8;
  s16x8 hv, lv;
#pragma unroll
  for (int j = 0; j < 8; ++j) {
    float f = d[j] * rs * gsr[j] + gbr[j];
    short h, l; split_bf16(f, h, l);
    hv[j] = h; lv[j] = l;
  }
  *(s16x8*)(oh + (size_t)row * DM + lane * 8) = hv;
  *(s16x8*)(ol + (size_t)row * DM + lane * 8) = lv;
}

// ---------------- LayerNorm fp32 out (head path) ----------------
__global__ __launch_bounds__(64) void ln_kernel(
    const float* __restrict__ x, const float* __restrict__ gs,
    const float* __restrict__ gb, float* __restrict__ out) {
  int row = blockIdx.x, lane = threadIdx.x;
  const float* xr = x + (size_t)row * DM + lane * 8;
  float4 v0 = *(const float4*)xr;
  float4 v1 = *(const float4*)(xr + 4);
  float v[8] = {v0.x, v0.y, v0.z, v0.w, v1.x, v1.y, v1.z, v1.w};
  float s = 0.f;
#pragma unroll
  for (int j = 0; j < 8; ++j) s += v[j];
  for (int m = 1; m < 64; m <<= 1) s += __shfl_xor(s, m, 64);
  float mu = s * (1.0f / DM);
  float d[8], ss = 0.f;
#pragma unroll
  for (int j = 0; j < 8; ++j) { d[j] = v[j] - mu; ss += d[j] * d[j]; }
  for (int m = 1; m < 64; m <<= 1) ss += __shfl_xor(ss, m, 64);
  float rs = 1.0f / sqrtf(ss * (1.0f / DM) + 1e-5f);
  const float* gsr = gs + lane * 8;
  const float* gbr = gb + lane * 8;
  float* orow = out + (size_t)row * DM + lane * 8;
  float r[8];
#pragma unroll
  for (int j = 0; j < 8; ++j) r[j] = d[j] * rs * gsr[j] + gbr[j];
  *(float4*)orow       = make_float4(r[0], r[1], r[2], r[3]);
  *(float4*)(orow + 4) = make_float4(r[4], r[5], r[6], r[7]);
}

// ---------------- split-bf16 MFMA GEMM 128x128 (pre-split A and W) ----------------
// EPI: 1 = qkv (q,k -> Ch/Cl stride 1024; v -> vT transposed), 2 = bias+gelu+split-out,
//      3 = bias+residual fp32 out
template <int EPI>
__global__ __launch_bounds__(256) void mgemm_kernel(
    const short* __restrict__ Ah, const short* __restrict__ Al,
    const short* __restrict__ Wh, const short* __restrict__ Wl,
    const float* __restrict__ bias, const float* __restrict__ res,
    float* __restrict__ Cf, short* __restrict__ Ch, short* __restrict__ Cl,
    short* __restrict__ vTh, short* __restrict__ vTl,
    int M, int N, int K) {
  __shared__ short As[2][128 * 40];   // [hi/lo][row][k(32)+pad8]
  __shared__ short Ws[2][128 * 40];
  int tid = threadIdx.x;
  int lane = tid & 63, w = tid >> 6;
  int wr = w >> 1, wc = w & 1;
  int row0 = blockIdx.y * 128, col0 = blockIdx.x * 128;
  int srow = tid >> 1, skc = (tid & 1) * 16;
  const short* Ahp = Ah + (size_t)(row0 + srow) * K + skc;
  const short* Alp = Al + (size_t)(row0 + srow) * K + skc;
  const short* Whp = Wh + (size_t)(col0 + srow) * K + skc;
  const short* Wlp = Wl + (size_t)(col0 + srow) * K + skc;
  int fr = lane & 15, fk = (lane >> 4) * 8;
  f32x4 acc[16];
#pragma unroll
  for (int i = 0; i < 16; ++i) acc[i] = (f32x4){0.f, 0.f, 0.f, 0.f};
  s16x8 rA0 = *(const s16x8*)(Ahp);
  s16x8 rA1 = *(const s16x8*)(Ahp + 8);
  s16x8 rA2 = *(const s16x8*)(Alp);
  s16x8 rA3 = *(const s16x8*)(Alp + 8);
  s16x8 rW0 = *(const s16x8*)(Whp);
  s16x8 rW1 = *(const s16x8*)(Whp + 8);
  s16x8 rW2 = *(const s16x8*)(Wlp);
  s16x8 rW3 = *(const s16x8*)(Wlp + 8);
  for (int ks = 0; ks < K; ks += 32) {
    __syncthreads();
    *(s16x8*)&As[0][srow * 40 + skc]     = rA0;
    *(s16x8*)&As[0][srow * 40 + skc + 8] = rA1;
    *(s16x8*)&As[1][srow * 40 + skc]     = rA2;
    *(s16x8*)&As[1][srow * 40 + skc + 8] = rA3;
    *(s16x8*)&Ws[0][srow * 40 + skc]     = rW0;
    *(s16x8*)&Ws[0][srow * 40 + skc + 8] = rW1;
    *(s16x8*)&Ws[1][srow * 40 + skc]     = rW2;
    *(s16x8*)&Ws[1][srow * 40 + skc + 8] = rW3;
    __syncthreads();
    if (ks + 32 < K) {
      rA0 = *(const s16x8*)(Ahp + ks + 32);
      rA1 = *(const s16x8*)(Ahp + ks + 40);
      rA2 = *(const s16x8*)(Alp + ks + 32);
      rA3 = *(const s16x8*)(Alp + ks + 40);
      rW0 = *(const s16x8*)(Whp + ks + 32);
      rW1 = *(const s16x8*)(Whp + ks + 40);
      rW2 = *(const s16x8*)(Wlp + ks + 32);
      rW3 = *(const s16x8*)(Wlp + ks + 40);
    }
    s16x8 bh_[4], bl_[4];
#pragma unroll
    for (int t = 0; t < 4; ++t) {
      bh_[t] = *(const s16x8*)&Ws[0][(wc * 64 + t * 16 + fr) * 40 + fk];
      bl_[t] = *(const s16x8*)&Ws[1][(wc * 64 + t * 16 + fr) * 40 + fk];
    }
#pragma unroll
    for (int a = 0; a < 4; ++a) {
      s16x8 ah_ = *(const s16x8*)&As[0][(wr * 64 + a * 16 + fr) * 40 + fk];
      s16x8 al_ = *(const s16x8*)&As[1][(wr * 64 + a * 16 + fr) * 40 + fk];
#pragma unroll
      for (int t = 0; t < 4; ++t) {
        f32x4 c = acc[a * 4 + t];
        c = MFMA(ah_, bh_[t], c);
        c = MFMA(ah_, bl_[t], c);
        c = MFMA(al_, bh_[t], c);
        acc[a * 4 + t] = c;
      }
    }
  }
  int fq = lane >> 4;
  if (EPI == 1) {
    int bidx = row0 / LL;
    int j0 = row0 - bidx * LL + wr * 64;
#pragma unroll
    for (int a = 0; a < 4; ++a) {
#pragma unroll
      for (int t = 0; t < 4; ++t) {
        int c = col0 + wc * 64 + t * 16 + fr;
        f32x4 v = acc[a * 4 + t];
        if (col0 < 1024) {  // q,k -> row-major stride 1024
#pragma unroll
          for (int r = 0; r < 4; ++r) {
            int row = row0 + wr * 64 + a * 16 + fq * 4 + r;
            size_t off = (size_t)row * 1024 + c;
            short h, l; split_bf16(v[r], h, l);
            Ch[off] = h; Cl[off] = l;
          }
        } else {            // v -> transposed [(b*8+h)*64+d][LL], 4 rows packed per store
          int vcol = c - 1024;
          size_t vidx = ((size_t)(bidx * 8 + (vcol >> 6)) * 64 + (vcol & 63)) * LL
                        + j0 + a * 16 + fq * 4;
          short4 hv, lv;
          short h, l;
          split_bf16(v[0], h, l); hv.x = h; lv.x = l;
          split_bf16(v[1], h, l); hv.y = h; lv.y = l;
          split_bf16(v[2], h, l); hv.z = h; lv.z = l;
          split_bf16(v[3], h, l); hv.w = h; lv.w = l;
          *(short4*)(vTh + vidx) = hv;
          *(short4*)(vTl + vidx) = lv;
        }
      }
    }
  } else {
#pragma unroll
    for (int a = 0; a < 4; ++a) {
#pragma unroll
      for (int t = 0; t < 4; ++t) {
#pragma unroll
        for (int r = 0; r < 4; ++r) {
          int row = row0 + wr * 64 + a * 16 + fq * 4 + r;
          int c   = col0 + wc * 64 + t * 16 + fr;
          size_t off = (size_t)row * N + c;
          float v = acc[a * 4 + t][r] + bias[c];
          if (EPI == 2) {
            v = gelu_f(v);
            short h, l; split_bf16(v, h, l);
            Ch[off] = h; Cl[off] = l;
          } else {
            Cf[off] = v + res[off];
          }
        }
      }
    }
  }
}

// ---------------- split-bf16 MFMA flash attention v3 ----------------
// K staged in LDS (2 barriers/jt); V^T read direct from pre-transposed global (L1-resident);
// P round-trips wave-local LDS (no barrier).
__global__ __launch_bounds__(256) void mattn_kernel(
    const short* __restrict__ qkh, const short* __restrict__ qkl,
    const short* __restrict__ vTh, const short* __restrict__ vTl,
    short* __restrict__ oh, short* __restrict__ ol) {
  __shared__ short Ks[2][64 * 72];
  __shared__ short Ps[2][64 * 72];
  int it = blockIdx.x, bh = blockIdx.y;
  int b = bh >> 3, h = bh & 7;
  int tid = threadIdx.x, lane = tid & 63, w = tid >> 6;
  int fr = lane & 15, fq = lane >> 4, fk = fq * 8;
  size_t rowbase = (size_t)b * LL;
  s16x8 qfh[2], qfl[2];
  {
    size_t qoff = (size_t)(rowbase + it * 64 + w * 16 + fr) * 1024 + h * DH;
    qfh[0] = *(const s16x8*)(qkh + qoff + fk);
    qfh[1] = *(const s16x8*)(qkh + qoff + 32 + fk);
    qfl[0] = *(const s16x8*)(qkl + qoff + fk);
    qfl[1] = *(const s16x8*)(qkl + qoff + 32 + fk);
  }
  const short* vbh = vTh + (size_t)(b * 8 + h) * 64 * LL;
  const short* vbl = vTl + (size_t)(b * 8 + h) * 64 * LL;
  float m_i[4], l_i[4];
  f32x4 oac[4];
#pragma unroll
  for (int r = 0; r < 4; ++r) { m_i[r] = -INFINITY; l_i[r] = 0.f; }
#pragma unroll
  for (int t = 0; t < 4; ++t) oac[t] = (f32x4){0.f, 0.f, 0.f, 0.f};
  int kjr = tid >> 2, kc0 = (tid & 3) * 16;
  for (int jt = 0; jt < LL / 64; ++jt) {
    size_t kbase = (size_t)(rowbase + jt * 64 + kjr) * 1024 + 512 + h * DH + kc0;
    s16x8 k0 = *(const s16x8*)(qkh + kbase);
    s16x8 k1 = *(const s16x8*)(qkh + kbase + 8);
    s16x8 k2 = *(const s16x8*)(qkl + kbase);
    s16x8 k3 = *(const s16x8*)(qkl + kbase + 8);
    __syncthreads();   // prev QK^T K-reads done
    *(s16x8*)&Ks[0][kjr * 72 + kc0]     = k0;
    *(s16x8*)&Ks[0][kjr * 72 + kc0 + 8] = k1;
    *(s16x8*)&Ks[1][kjr * 72 + kc0]     = k2;
    *(s16x8*)&Ks[1][kjr * 72 + kc0 + 8] = k3;
    __syncthreads();
    // QK^T
    f32x4 s[4];
#pragma unroll
    for (int t = 0; t < 4; ++t) s[t] = (f32x4){0.f, 0.f, 0.f, 0.f};
#pragma unroll
    for (int ks = 0; ks < 2; ++ks) {
#pragma unroll
      for (int t = 0; t < 4; ++t) {
        s16x8 kh_ = *(const s16x8*)&Ks[0][(t * 16 + fr) * 72 + ks * 32 + fk];
        s16x8 kl_ = *(const s16x8*)&Ks[1][(t * 16 + fr) * 72 + ks * 32 + fk];
        s[t] = MFMA(qfh[ks], kh_, s[t]);
        s[t] = MFMA(qfh[ks], kl_, s[t]);
        s[t] = MFMA(qfl[ks], kh_, s[t]);
      }
    }
    // V^T fragments direct from global (issued early; latency hides under softmax)
    s16x8 vh_[2][4], vl_[2][4];
#pragma unroll
    for (int ks = 0; ks < 2; ++ks) {
#pragma unroll
      for (int t = 0; t < 4; ++t) {
        size_t voff = (size_t)(t * 16 + fr) * LL + jt * 64 + ks * 32 + fk;
        vh_[ks][t] = *(const s16x8*)(vbh + voff);
        vl_[ks][t] = *(const s16x8*)(vbl + voff);
      }
    }
    // online softmax
#pragma unroll
    for (int r = 0; r < 4; ++r) {
      float s0 = s[0][r] * 0.125f, s1 = s[1][r] * 0.125f;
      float s2 = s[2][r] * 0.125f, s3 = s[3][r] * 0.125f;
      float mr = fmaxf(fmaxf(s0, s1), fmaxf(s2, s3));
      mr = fmaxf(mr, __shfl_xor(mr, 1, 64));
      mr = fmaxf(mr, __shfl_xor(mr, 2, 64));
      mr = fmaxf(mr, __shfl_xor(mr, 4, 64));
      mr = fmaxf(mr, __shfl_xor(mr, 8, 64));
      float mn = fmaxf(m_i[r], mr);
      float al = expf(m_i[r] - mn);
      float p0 = expf(s0 - mn), p1 = expf(s1 - mn);
      float p2 = expf(s2 - mn), p3 = expf(s3 - mn);
      float ps = p0 + p1 + p2 + p3;
      ps += __shfl_xor(ps, 1, 64); ps += __shfl_xor(ps, 2, 64);
      ps += __shfl_xor(ps, 4, 64); ps += __shfl_xor(ps, 8, 64);
      l_i[r] = l_i[r] * al + ps;
      m_i[r] = mn;
      oac[0][r] *= al; oac[1][r] *= al; oac[2][r] *= al; oac[3][r] *= al;
      int prow = (w * 16 + fq * 4 + r) * 72;
      short hh_, ll_;
      split_bf16(p0, hh_, ll_); Ps[0][prow + fr]      = hh_; Ps[1][prow + fr]      = ll_;
      split_bf16(p1, hh_, ll_); Ps[0][prow + 16 + fr] = hh_; Ps[1][prow + 16 + fr] = ll_;
      split_bf16(p2, hh_, ll_); Ps[0][prow + 32 + fr] = hh_; Ps[1][prow + 32 + fr] = ll_;
      split_bf16(p3, hh_, ll_); Ps[0][prow + 48 + fr] = hh_; Ps[1][prow + 48 + fr] = ll_;
    }
    // PV (Ps reads are wave-local rows: same-wave DS ordering, no barrier)
#pragma unroll
    for (int ks = 0; ks < 2; ++ks) {
      s16x8 ph_ = *(const s16x8*)&Ps[0][(w * 16 + fr) * 72 + ks * 32 + fk];
      s16x8 pl_ = *(const s16x8*)&Ps[1][(w * 16 + fr) * 72 + ks * 32 + fk];
#pragma unroll
      for (int t = 0; t < 4; ++t) {
        oac[t] = MFMA(ph_, vh_[ks][t], oac[t]);
        oac[t] = MFMA(ph_, vl_[ks][t], oac[t]);
        oac[t] = MFMA(pl_, vh_[ks][t], oac[t]);
      }
    }
  }
#pragma unroll
  for (int r = 0; r < 4; ++r) {
    float inv = 1.0f / l_i[r];
    size_t row = rowbase + it * 64 + w * 16 + fq * 4 + r;
#pragma unroll
    for (int t = 0; t < 4; ++t) {
      float v = oac[t][r] * inv;
      short hh_, ll_; split_bf16(v, hh_, ll_);
      size_t off = row * DM + h * DH + t * 16 + fr;
      oh[off] = hh_; ol[off] = ll_;
    }
  }
}

// ---------------- max-pool over sequence (two stage) ----------------
__global__ __launch_bounds__(256) void poolmax1_kernel(const float* __restrict__ x,
                                                       float* __restrict__ partial) {
  int ch = blockIdx.x, b = blockIdx.y, tid = threadIdx.x;
  const float* p = x + ((size_t)b * LL + ch * 128) * DM;
  float m0 = -INFINITY, m1 = -INFINITY;
#pragma unroll 4
  for (int l = 0; l < 128; ++l) {
    m0 = fmaxf(m0, p[(size_t)l * DM + tid]);
    m1 = fmaxf(m1, p[(size_t)l * DM + tid + 256]);
  }
  partial[(size_t)(b * TO + ch) * DM + tid] = m0;
  partial[(size_t)(b * TO + ch) * DM + tid + 256] = m1;
}

__global__ __launch_bounds__(256) void poolmax2_kernel(const float* __restrict__ partial,
                                                       float* __restrict__ pooled) {
  int idx = blockIdx.x * 256 + threadIdx.x;
  int b = idx >> 9, d = idx & 511;
  float m = -INFINITY;
#pragma unroll
  for (int c = 0; c < TO; ++c) m = fmaxf(m, partial[(size_t)(b * TO + c) * DM + d]);
  pooled[idx] = m;
}

// ---------------- head MLP ----------------
__global__ __launch_bounds__(256) void head1_kernel(const float* __restrict__ lnp,
                                                    const float* __restrict__ w,
                                                    const float* __restrict__ bb,
                                                    float* __restrict__ hid) {
  int idx = blockIdx.x * 256 + threadIdx.x;
  int b = idx >> 10, n = idx & 1023;
  const float* xr = lnp + (size_t)b * DM;
  const float* wr = w + (size_t)n * DM;
  float s = 0.f;
  for (int k = 0; k < DM; k += 4) {
    float4 xv = *(const float4*)(xr + k);
    float4 wv = *(const float4*)(wr + k);
    s += xv.x * wv.x + xv.y * wv.y + xv.z * wv.z + xv.w * wv.w;
  }
  hid[idx] = gelu_f(s + bb[n]);
}

__global__ __launch_bounds__(128) void head2_kernel(const float* __restrict__ hid,
                                                    const float* __restrict__ w,
                                                    const float* __restrict__ bb,
                                                    float* __restrict__ dout) {
  int t = threadIdx.x;
  if (t < BN_ * NC) {
    int b = t / NC, n = t - b * NC;
    const float* xr = hid + (size_t)b * MLPD;
    const float* wr = w + (size_t)n * MLPD;
    float s = 0.f;
    for (int k = 0; k < MLPD; k += 4) {
      float4 xv = *(const float4*)(xr + k);
      float4 wv = *(const float4*)(wr + k);
      s += xv.x * wv.x + xv.y * wv.y + xv.z * wv.z + xv.w * wv.w;
    }
    dout[OUT_LOGITS + t] = s + bb[n];
  }
}

// ---------------- launch ----------------
extern "C" void kernel_launch(void* const* d_in, const int* in_sizes, int n_in,
                              void* d_out, int out_size, void* d_ws, size_t ws_size,
                              hipStream_t stream) {
  (void)in_sizes; (void)n_in; (void)out_size; (void)ws_size;
  const float* xyzs     = (const float*)d_in[0];
  const float* oldf     = (const float*)d_in[1];
  const float* conv_d_w = (const float*)d_in[2];
  const float* conv_f_w = (const float*)d_in[3];
  const float* pos_w    = (const float*)d_in[4];
  const float* pos_b    = (const float*)d_in[5];
  const float* contr_w  = (const float*)d_in[6];
  const float* contr_b  = (const float*)d_in[7];
  const float* ln1_s    = (const float*)d_in[8];
  const float* ln1_b    = (const float*)d_in[9];
  const float* qkv_w    = (const float*)d_in[10];
  const float* out_w    = (const float*)d_in[11];
  const float* out_b    = (const float*)d_in[12];
  const float* ln2_s    = (const float*)d_in[13];
  const float* ln2_b    = (const float*)d_in[14];
  const float* ff1_w    = (const float*)d_in[15];
  const float* ff1_b    = (const float*)d_in[16];
  const float* ff2_w    = (const float*)d_in[17];
  const float* ff2_b    = (const float*)d_in[18];
  const float* hl_s     = (const float*)d_in[19];
  const float* hl_b     = (const float*)d_in[20];
  const float* h1_w     = (const float*)d_in[21];
  const float* h1_b     = (const float*)d_in[22];
  const float* h2_w     = (const float*)d_in[23];
  const float* h2_b     = (const float*)d_in[24];
  float* dout = (float*)d_out;
  char* base = (char*)d_ws;
  auto alloc = [&](size_t bytes) { char* p = base; base += (bytes + 255) & ~(size_t)255; return p; };

  float* anchor = (float*)alloc((size_t)BN_ * TO * MM * 3 * 4);
  float* x      = (float*)alloc((size_t)BL * DM * 4);
  short* qkvh   = (short*)alloc((size_t)BL * 1024 * 2);   // q|k packed, stride 1024
  short* qkvl   = (short*)alloc((size_t)BL * 1024 * 2);
  short* vTh    = (short*)alloc((size_t)BN_ * NH * DH * LL * 2);
  short* vTl    = (short*)alloc((size_t)BN_ * NH * DH * LL * 2);
  short* atnh   = (short*)alloc((size_t)BL * DM * 2);
  short* atnl   = (short*)alloc((size_t)BL * DM * 2);
  short* hh     = (short*)alloc((size_t)BL * DM * 2);
  short* hl     = (short*)alloc((size_t)BL * DM * 2);
  short* wsh    = (short*)alloc((size_t)WTOT * 2);
  short* wsl    = (short*)alloc((size_t)WTOT * 2);
  float* partial= (float*)alloc((size_t)BN_ * TO * DM * 4);
  float* pooled = (float*)alloc((size_t)BN_ * DM * 4);
  float* lnp    = (float*)alloc((size_t)BN_ * DM * 4);
  float* hid    = (float*)alloc((size_t)BN_ * MLPD * 4);
  short* fh = qkvh;  // FF hidden aliases qkv (BL*1024 shorts, consumed by then)
  short* fl = qkvl;

  splitw_kernel<<<WTOT / 256, 256, 0, stream>>>(qkv_w, out_w, ff1_w, ff2_w, wsh, wsl);
  fps_kernel<<<BN_ * TO, 256, 0, stream>>>(xyzs, anchor);
  ballconv_kernel<<<BN_ * TO * MM, 64, 0, stream>>>(xyzs, oldf, anchor, conv_d_w, conv_f_w, dout);
  posx_kernel<<<(BL * DM) / 256, 256, 0, stream>>>(anchor, pos_w, pos_b, contr_w, contr_b, dout, x);

  for (int l = 0; l < 4; ++l) {
    ln_split_kernel<<<BL, 64, 0, stream>>>(x, ln1_s + l * DM, ln1_b + l * DM, hh, hl);
    mgemm_kernel<1><<<dim3(1536 / 128, BL / 128), 256, 0, stream>>>(
        hh, hl, wsh + WQOFF + (size_t)l * 786432, wsl + WQOFF + (size_t)l * 786432,
        nullptr, nullptr, nullptr, qkvh, qkvl, vTh, vTl, BL, 1536, DM);
    mattn_kernel<<<dim3(LL / 64, BN_ * NH), 256, 0, stream>>>(qkvh, qkvl, vTh, vTl, atnh, atnl);
    mgemm_kernel<3><<<dim3(DM / 128, BL / 128), 256, 0, stream>>>(
        atnh, atnl, wsh + WOOFF + (size_t)l * 262144, wsl + WOOFF + (size_t)l * 262144,
        out_b + l * DM, x, x, nullptr, nullptr, nullptr, nullptr, BL, DM, DM);
    ln_split_kernel<<<BL, 64, 0, stream>>>(x, ln2_s + l * DM, ln2_b + l * DM, hh, hl);
    mgemm_kernel<2><<<dim3(MLPD / 128, BL / 128), 256, 0, stream>>>(
        hh, hl, wsh + WF1OFF + (size_t)l * 524288, wsl + WF1OFF + (size_t)l * 524288,
        ff1_b + l * MLPD, nullptr, nullptr, fh, fl, nullptr, nullptr, BL, MLPD, DM);
    mgemm_kernel<3><<<dim3(DM / 128, BL / 128), 256, 0, stream>>>(
        fh, fl, wsh + WF2OFF + (size_t)l * 524288, wsl + WF2OFF + (size_t)l * 524288,
        ff2_b + l * DM, x, x, nullptr, nullptr, nullptr, nullptr, BL, DM, MLPD);
  }

  poolmax1_kernel<<<dim3(TO, BN_), 256, 0, stream>>>(x, partial);
  poolmax2_kernel<<<(BN_ * DM) / 256, 256, 0, stream>>>(partial, pooled);
  ln_kernel<<<BN_, 64, 0, stream>>>(pooled, hl_s, hl_b, lnp);
  head1_kernel<<<(BN_ * MLPD) / 256, 256, 0, stream>>>(lnp, h1_w, h1_b, hid);
  head2_kernel<<<1, 128, 0, stream>>>(hid, h2_w, h2_b, dout);
}

// Round 5
// 1638.566 us; speedup vs baseline: 1.0718x; 1.0718x over previous
//
#include <hip/hip_runtime.h>
#include <math.h>

// ---------------- problem constants ----------------
#define BN_  4
#define TT   24
#define NN   4096
#define TO   12
#define MM   128
#define LL   (TO*MM)          // 1536
#define BL   (BN_*LL)         // 6144
#define DM   512
#define NH   8
#define DH   64
#define MLPD 1024
#define NC   30

// output layout (floats): logits | contrastive | features
#define OUT_LOGITS 0
#define OUT_CONTR  (BN_*NC)                 // 120
#define OUT_FEATS  (OUT_CONTR + BL*DM)      // 120 + 3145728

// weight-split region offsets (in shorts)
#define NWQ   3145728   // 4*1536*512
#define NWO   1048576   // 4*512*512
#define NWF1  2097152   // 4*1024*512
#define NWF2  2097152   // 4*512*1024
#define WQOFF   0
#define WOOFF   (NWQ)
#define WF1OFF  (NWQ+NWO)
#define WF2OFF  (NWQ+NWO+NWF1)
#define WTOT    (NWQ+NWO+NWF1+NWF2)   // 8388608

typedef __attribute__((ext_vector_type(8))) short s16x8;
typedef __attribute__((ext_vector_type(4))) float f32x4;
#define MFMA(a,b,c) __builtin_amdgcn_mfma_f32_16x16x32_bf16(a,b,c,0,0,0)

// split fp32 -> bf16 hi (truncate) + bf16 lo (truncated residual); a ~= hi + lo
__device__ __forceinline__ void split_bf16(float a, short &h, short &l) {
  unsigned u = __float_as_uint(a);
  h = (short)(u >> 16);
  float ah = __uint_as_float(u & 0xffff0000u);
  float al = a - ah;
  l = (short)(__float_as_uint(al) >> 16);
}

// exact (non-FMA-contracted) squared distance, matching XLA's mul+add order
__device__ __forceinline__ float d2_3(float ax, float ay, float az,
                                      float bx, float by, float bz) {
#pragma clang fp contract(off)
  float dx = ax - bx, dy = ay - by, dz = az - bz;
  float dx2 = dx * dx, dy2 = dy * dy, dz2 = dz * dz;
  return (dx2 + dy2) + dz2;
}

__device__ __forceinline__ float gelu_f(float v) {
  return 0.5f * v * (1.0f + erff(v * 0.70710678118654752440f));
}

// ---------------- one-time weight split ----------------
__global__ __launch_bounds__(256) void splitw_kernel(
    const float* __restrict__ qkv_w, const float* __restrict__ out_w,
    const float* __restrict__ ff1_w, const float* __restrict__ ff2_w,
    short* __restrict__ wh, short* __restrict__ wl) {
  int i = blockIdx.x * 256 + threadIdx.x;
  const float* src; int off;
  if (i < WOOFF)        { src = qkv_w; off = i; }
  else if (i < WF1OFF)  { src = out_w; off = i - WOOFF; }
  else if (i < WF2OFF)  { src = ff1_w; off = i - WF1OFF; }
  else                  { src = ff2_w; off = i - WF2OFF; }
  float v = src[off];
  short h, l; split_bf16(v, h, l);
  wh[i] = h; wl[i] = l;
}

// ---------------- FPS v2: one block per (b, ti), 1 barrier/iter ----------------
__global__ __launch_bounds__(256) void fps_kernel(const float* __restrict__ xyzs,
                                                  float* __restrict__ anchor) {
  __shared__ float sx[NN], sy[NN], sz[NN];
  __shared__ unsigned long long skey[2][4];
  int blk = blockIdx.x;
  int b = blk / TO, ti = blk - b * TO;
  const float* src = xyzs + ((size_t)(b * TT + 2 * ti)) * NN * 3;
  int tid = threadIdx.x;
  float dist[16], px[16], py[16], pz[16];
#pragma unroll
  for (int s = 0; s < 16; ++s) {
    int p = tid + s * 256;
    px[s] = src[p * 3 + 0]; py[s] = src[p * 3 + 1]; pz[s] = src[p * 3 + 2];
    sx[p] = px[s]; sy[p] = py[s]; sz[p] = pz[s];
    dist[s] = 1e10f;
  }
  __syncthreads();
  float lx = sx[0], ly = sy[0], lz = sz[0];
  float* aout = anchor + (size_t)blk * MM * 3;
  if (tid == 0) { aout[0] = lx; aout[1] = ly; aout[2] = lz; }
  for (int j = 1; j < MM; ++j) {
    unsigned long long best = 0;
#pragma unroll
    for (int s = 0; s < 16; ++s) {
      float d2 = d2_3(px[s], py[s], pz[s], lx, ly, lz);
      float dn = fminf(dist[s], d2);
      dist[s] = dn;
      unsigned long long key = ((unsigned long long)__float_as_uint(dn) << 12)
                               | (unsigned)(4095 - (tid + s * 256));
      best = key > best ? key : best;
    }
#pragma unroll
    for (int m = 1; m < 64; m <<= 1) {
      unsigned long long o = __shfl_xor(best, m, 64);
      best = o > best ? o : best;
    }
    if ((tid & 63) == 0) skey[j & 1][tid >> 6] = best;
    __syncthreads();
    unsigned long long b0 = skey[j & 1][0], b1 = skey[j & 1][1];
    unsigned long long b2 = skey[j & 1][2], b3 = skey[j & 1][3];
    unsigned long long bb = b0 > b1 ? b0 : b1;
    unsigned long long cc = b2 > b3 ? b2 : b3;
    bb = bb > cc ? bb : cc;
    int bi = 4095 - (int)(bb & 0xFFFull);
    lx = sx[bi]; ly = sy[bi]; lz = sz[bi];
    if (tid == 0) { aout[j * 3 + 0] = lx; aout[j * 3 + 1] = ly; aout[j * 3 + 2] = lz; }
  }
}

// ---------------- ball query + p4dconv + max-pool: one wave per (b,ti,m) ----------------
__global__ __launch_bounds__(64) void ballconv_kernel(
    const float* __restrict__ xyzs, const float* __restrict__ oldf,
    const float* __restrict__ anchor,
    const float* __restrict__ wdw, const float* __restrict__ wfw,
    float* __restrict__ dout) {
  __shared__ int   sidx[32];
  __shared__ float sdisp[32][4];
  __shared__ float sfeat[32][2];
  int blk = blockIdx.x;
  int b = blk / (TO * MM);
  int rem = blk - b * (TO * MM);
  int ti = rem / MM;
  int lane = threadIdx.x;
  const float* ap = anchor + (size_t)blk * 3;
  float ax = ap[0], ay = ap[1], az = ap[2];
  int d0 = lane * 8;
  float4 wd[8]; float2 wf[8];
#pragma unroll
  for (int jd = 0; jd < 8; ++jd) {
    wd[jd] = *(const float4*)(wdw + (d0 + jd) * 4);
    wf[jd] = *(const float2*)(wfw + (d0 + jd) * 2);
  }
  float fmx[8];
#pragma unroll
  for (int jd = 0; jd < 8; ++jd) fmx[jd] = -INFINITY;

  for (int o = -1; o <= 1; ++o) {
    int tp = 1 + 2 * ti + o;
    int orig = (tp == 0) ? 0 : tp - 1;
    const float* nx = xyzs + ((size_t)(b * TT + orig)) * NN * 3;
    const float* nf = oldf + ((size_t)(b * TT + orig)) * 2 * NN;
    int cnt = 0;
    for (int base = 0; base < NN && cnt < 32; base += 64) {
      int p = base + lane;
      float d2 = d2_3(ax, ay, az, nx[p * 3], nx[p * 3 + 1], nx[p * 3 + 2]);
      bool in = d2 < 0.09f;
      unsigned long long mask = __ballot(in);
      int pos = __popcll(mask & ((1ull << lane) - 1ull));
      if (in && (cnt + pos) < 32) sidx[cnt + pos] = p;
      cnt += __popcll(mask);
    }
    __syncthreads();
    int used = cnt < 32 ? cnt : 32;
    if (lane < 32 && lane >= used) sidx[lane] = (used > 0) ? sidx[0] : 0;
    __syncthreads();
    if (lane < 32) {
      int p = sidx[lane];
      sdisp[lane][0] = nx[p * 3 + 0] - ax;
      sdisp[lane][1] = nx[p * 3 + 1] - ay;
      sdisp[lane][2] = nx[p * 3 + 2] - az;
      sdisp[lane][3] = (float)o;
      sfeat[lane][0] = nf[p];
      sfeat[lane][1] = nf[NN + p];
    }
    __syncthreads();
    for (int k = 0; k < 32; ++k) {
      float p0 = sdisp[k][0], p1 = sdisp[k][1], p2 = sdisp[k][2], p3 = sdisp[k][3];
      float f0 = sfeat[k][0], f1 = sfeat[k][1];
#pragma unroll
      for (int jd = 0; jd < 8; ++jd) {
        float de = wd[jd].x * p0 + wd[jd].y * p1 + wd[jd].z * p2 + wd[jd].w * p3;
        float fe = wf[jd].x * f0 + wf[jd].y * f1;
        fmx[jd] = fmaxf(fmx[jd], fe * de);
      }
    }
    __syncthreads();
  }
  float* fout = dout + OUT_FEATS + (size_t)blk * DM + d0;
#pragma unroll
  for (int jd = 0; jd < 8; jd += 4)
    *(float4*)(fout + jd) = make_float4(fmx[jd], fmx[jd + 1], fmx[jd + 2], fmx[jd + 3]);
}

// ---------------- pos/contrastive embed + x = relu(pos + features) ----------------
__global__ __launch_bounds__(256) void posx_kernel(
    const float* __restrict__ anchor,
    const float* __restrict__ pw, const float* __restrict__ pb,
    const float* __restrict__ cw, const float* __restrict__ cb,
    float* __restrict__ dout, float* __restrict__ x) {
  int idx = blockIdx.x * 256 + threadIdx.x;
  int bl = idx >> 9, d = idx & 511;
  int ti = (bl % LL) / MM;
  const float* ap = anchor + (size_t)bl * 3;
  float c0 = ap[0], c1 = ap[1], c2 = ap[2], c3 = (float)(ti + 1);
  float4 pwv = *(const float4*)(pw + d * 4);
  float4 cwv = *(const float4*)(cw + d * 4);
  float pos = pwv.x * c0 + pwv.y * c1 + pwv.z * c2 + pwv.w * c3 + pb[d];
  float con = cwv.x * c0 + cwv.y * c1 + cwv.z * c2 + cwv.w * c3 + cb[d];
  dout[OUT_CONTR + (size_t)idx] = con;
  float v = pos + dout[OUT_FEATS + (size_t)idx];
  x[idx] = v > 0.0f ? v : 0.0f;
}

// ---------------- LayerNorm -> split bf16 hi/lo: one wave per row ----------------
__global__ __launch_bounds__(64) void ln_split_kernel(
    const float* __restrict__ x, const float* __restrict__ gs,
    const float* __restrict__ gb, short* __restrict__ oh, short* __restrict__ ol) {
  int row = blockIdx.x, lane = threadIdx.x;
  const float* xr = x + (size_t)row * DM + lane * 8;
  float4 v0 = *(const float4*)xr;
  float4 v1 = *(const float4*)(xr + 4);
  float v[8] = {v0.x, v0.y, v0.z, v0.w, v1.x, v1.y, v1.z, v1.w};
  float s = 0.f;
#pragma unroll
  for (int j = 0; j < 8; ++j) s += v[j];
  for (int m = 1; m < 64; m <<= 1) s += __shfl_xor(s, m, 64);
  float mu = s * (1.0f / DM);
  float d[8], ss = 0.f;
#pragma unroll
  for (int j = 0; j < 8; ++j) { d[j] = v[j] - mu; ss += d[j] * d[j]; }
  for (int m = 1; m < 64; m <<= 1) ss += __shfl_xor(ss, m, 64);
  float rs = 1.0f / sqrtf(ss * (1.0f / DM) + 1e-5f);
  const float* gsr = gs + lane * 8;
  const float* gbr = gb + lane * 8;
  s16x8 hv, lv;
#pragma unroll
  for (int j = 0; j < 8; ++j) {
    float f = d[j] * rs * gsr[j] + gbr[j];
    short h, l; split_bf16(f, h, l);
    hv[j] = h; lv[j] = l;
  }
  *(s16x8*)(oh + (size_t)row * DM + lane * 8) = hv;
  *(s16x8*)(ol + (size_t)row * DM + lane * 8) = lv;
}

// ---------------- LayerNorm fp32 out (head path) ----------------
__global__ __launch_bounds__(64) void ln_kernel(
    const float* __restrict__ x, const float* __restrict__ gs,
    const float* __restrict__ gb, float* __restrict__ out) {
  int row = blockIdx.x, lane = threadIdx.x;
  const float* xr = x + (size_t)row * DM + lane * 8;
  float4 v0 = *(const float4*)xr;
  float4 v1 = *(const float4*)(xr + 4);
  float v[8] = {v0.x, v0.y, v0.z, v0.w, v1.x, v1.y, v1.z, v1.w};
  float s = 0.f;
#pragma unroll
  for (int j = 0; j < 8; ++j) s += v[j];
  for (int m = 1; m < 64; m <<= 1) s += __shfl_xor(s, m, 64);
  float mu = s * (1.0f / DM);
  float d[8], ss = 0.f;
#pragma unroll
  for (int j = 0; j < 8; ++j) { d[j] = v[j] - mu; ss += d[j] * d[j]; }
  for (int m = 1; m < 64; m <<= 1) ss += __shfl_xor(ss, m, 64);
  float rs = 1.0f / sqrtf(ss * (1.0f / DM) + 1e-5f);
  const float* gsr = gs + lane * 8;
  const float* gbr = gb + lane * 8;
  float* orow = out + (size_t)row * DM + lane * 8;
  float r[8];
#pragma unroll
  for (int j = 0; j < 8; ++j) r[j] = d[j] * rs * gsr[j] + gbr[j];
  *(float4*)orow       = make_float4(r[0], r[1], r[2], r[3]);
  *(float4*)(orow + 4) = make_float4(r[4], r[5], r[6], r[7]);
}

// ---------------- split-bf16 MFMA GEMM 128x128 (pre-split A and W) ----------------
// EPI: 1 = qkv (q scaled by 0.125, q,k -> Ch/Cl stride 1024; v -> vT transposed),
//      2 = bias+gelu+split-out, 3 = bias+residual fp32 out
template <int EPI>
__global__ __launch_bounds__(256) void mgemm_kernel(
    const short* __restrict__ Ah, const short* __restrict__ Al,
    const short* __restrict__ Wh, const short* __restrict__ Wl,
    const float* __restrict__ bias, const float* __restrict__ res,
    float* __restrict__ Cf, short* __restrict__ Ch, short* __restrict__ Cl,
    short* __restrict__ vTh, short* __restrict__ vTl,
    int M, int N, int K) {
  __shared__ short As[2][128 * 40];   // [hi/lo][row][k(32)+pad8]
  __shared__ short Ws[2][128 * 40];
  int tid = threadIdx.x;
  int lane = tid & 63, w = tid >> 6;
  int wr = w >> 1, wc = w & 1;
  int row0 = blockIdx.y * 128, col0 = blockIdx.x * 128;
  int srow = tid >> 1, skc = (tid & 1) * 16;
  const short* Ahp = Ah + (size_t)(row0 + srow) * K + skc;
  const short* Alp = Al + (size_t)(row0 + srow) * K + skc;
  const short* Whp = Wh + (size_t)(col0 + srow) * K + skc;
  const short* Wlp = Wl + (size_t)(col0 + srow) * K + skc;
  int fr = lane & 15, fk = (lane >> 4) * 8;
  f32x4 acc[16];
#pragma unroll
  for (int i = 0; i < 16; ++i) acc[i] = (f32x4){0.f, 0.f, 0.f, 0.f};
  s16x8 rA0 = *(const s16x8*)(Ahp);
  s16x8 rA1 = *(const s16x8*)(Ahp + 8);
  s16x8 rA2 = *(const s16x8*)(Alp);
  s16x8 rA3 = *(const s16x8*)(Alp + 8);
  s16x8 rW0 = *(const s16x8*)(Whp);
  s16x8 rW1 = *(const s16x8*)(Whp + 8);
  s16x8 rW2 = *(const s16x8*)(Wlp);
  s16x8 rW3 = *(const s16x8*)(Wlp + 8);
  for (int ks = 0; ks < K; ks += 32) {
    __syncthreads();
    *(s16x8*)&As[0][srow * 40 + skc]     = rA0;
    *(s16x8*)&As[0][srow * 40 + skc + 8] = rA1;
    *(s16x8*)&As[1][srow * 40 + skc]     = rA2;
    *(s16x8*)&As[1][srow * 40 + skc + 8] = rA3;
    *(s16x8*)&Ws[0][srow * 40 + skc]     = rW0;
    *(s16x8*)&Ws[0][srow * 40 + skc + 8] = rW1;
    *(s16x8*)&Ws[1][srow * 40 + skc]     = rW2;
    *(s16x8*)&Ws[1][srow * 40 + skc + 8] = rW3;
    __syncthreads();
    if (ks + 32 < K) {
      rA0 = *(const s16x8*)(Ahp + ks + 32);
      rA1 = *(const s16x8*)(Ahp + ks + 40);
      rA2 = *(const s16x8*)(Alp + ks + 32);
      rA3 = *(const s16x8*)(Alp + ks + 40);
      rW0 = *(const s16x8*)(Whp + ks + 32);
      rW1 = *(const s16x8*)(Whp + ks + 40);
      rW2 = *(const s16x8*)(Wlp + ks + 32);
      rW3 = *(const s16x8*)(Wlp + ks + 40);
    }
    s16x8 bh_[4], bl_[4];
#pragma unroll
    for (int t = 0; t < 4; ++t) {
      bh_[t] = *(const s16x8*)&Ws[0][(wc * 64 + t * 16 + fr) * 40 + fk];
      bl_[t] = *(const s16x8*)&Ws[1][(wc * 64 + t * 16 + fr) * 40 + fk];
    }
#pragma unroll
    for (int a = 0; a < 4; ++a) {
      s16x8 ah_ = *(const s16x8*)&As[0][(wr * 64 + a * 16 + fr) * 40 + fk];
      s16x8 al_ = *(const s16x8*)&As[1][(wr * 64 + a * 16 + fr) * 40 + fk];
#pragma unroll
      for (int t = 0; t < 4; ++t) {
        f32x4 c = acc[a * 4 + t];
        c = MFMA(ah_, bh_[t], c);
        c = MFMA(ah_, bl_[t], c);
        c = MFMA(al_, bh_[t], c);
        acc[a * 4 + t] = c;
      }
    }
  }
  int fq = lane >> 4;
  if (EPI == 1) {
    int bidx = row0 / LL;
    int j0 = row0 - bidx * LL + wr * 64;
    float qscale = (col0 < 512) ? 0.125f : 1.0f;  // exact pow2: commutes with split
#pragma unroll
    for (int a = 0; a < 4; ++a) {
#pragma unroll
      for (int t = 0; t < 4; ++t) {
        int c = col0 + wc * 64 + t * 16 + fr;
        f32x4 v = acc[a * 4 + t];
        if (col0 < 1024) {  // q,k -> row-major stride 1024
#pragma unroll
          for (int r = 0; r < 4; ++r) {
            int row = row0 + wr * 64 + a * 16 + fq * 4 + r;
            size_t off = (size_t)row * 1024 + c;
            short h, l; split_bf16(v[r] * qscale, h, l);
            Ch[off] = h; Cl[off] = l;
          }
        } else {            // v -> transposed [(b*8+h)*64+d][LL], 4 rows packed per store
          int vcol = c - 1024;
          size_t vidx = ((size_t)(bidx * 8 + (vcol >> 6)) * 64 + (vcol & 63)) * LL
                        + j0 + a * 16 + fq * 4;
          short4 hv, lv;
          short h, l;
          split_bf16(v[0], h, l); hv.x = h; lv.x = l;
          split_bf16(v[1], h, l); hv.y = h; lv.y = l;
          split_bf16(v[2], h, l); hv.z = h; lv.z = l;
          split_bf16(v[3], h, l); hv.w = h; lv.w = l;
          *(short4*)(vTh + vidx) = hv;
          *(short4*)(vTl + vidx) = lv;
        }
      }
    }
  } else {
#pragma unroll
    for (int a = 0; a < 4; ++a) {
#pragma unroll
      for (int t = 0; t < 4; ++t) {
#pragma unroll
        for (int r = 0; r < 4; ++r) {
          int row = row0 + wr * 64 + a * 16 + fq * 4 + r;
          int c   = col0 + wc * 64 + t * 16 + fr;
          size_t off = (size_t)row * N + c;
          float v = acc[a * 4 + t][r] + bias[c];
          if (EPI == 2) {
            v = gelu_f(v);
            short h, l; split_bf16(v, h, l);
            Ch[off] = h; Cl[off] = l;
          } else {
            Cf[off] = v + res[off];
          }
        }
      }
    }
  }
}

// ---------------- split-bf16 MFMA flash attention v5 ----------------
// K and V^T both staged in LDS with coalesced 16B loads (V^T from pre-transposed global);
// 2 barriers/jt; P round-trips wave-local LDS (no barrier). q pre-scaled by 0.125.
__global__ __launch_bounds__(256) void mattn_kernel(
    const short* __restrict__ qkh, const short* __restrict__ qkl,
    const short* __restrict__ vTh, const short* __restrict__ vTl,
    short* __restrict__ oh, short* __restrict__ ol) {
  __shared__ short Ks[2][64 * 72];
  __shared__ short Vs[2][64 * 72];
  __shared__ short Ps[2][64 * 72];
  int it = blockIdx.x, bh = blockIdx.y;
  int b = bh >> 3, h = bh & 7;
  int tid = threadIdx.x, lane = tid & 63, w = tid >> 6;
  int fr = lane & 15, fq = lane >> 4, fk = fq * 8;
  size_t rowbase = (size_t)b * LL;
  s16x8 qfh[2], qfl[2];
  {
    size_t qoff = (size_t)(rowbase + it * 64 + w * 16 + fr) * 1024 + h * DH;
    qfh[0] = *(const s16x8*)(qkh + qoff + fk);
    qfh[1] = *(const s16x8*)(qkh + qoff + 32 + fk);
    qfl[0] = *(const s16x8*)(qkl + qoff + fk);
    qfl[1] = *(const s16x8*)(qkl + qoff + 32 + fk);
  }
  const short* vbh = vTh + (size_t)(b * 8 + h) * 64 * LL;
  const short* vbl = vTl + (size_t)(b * 8 + h) * 64 * LL;
  float m_i[4], l_i[4];
  f32x4 oac[4];
#pragma unroll
  for (int r = 0; r < 4; ++r) { m_i[r] = -INFINITY; l_i[r] = 0.f; }
#pragma unroll
  for (int t = 0; t < 4; ++t) oac[t] = (f32x4){0.f, 0.f, 0.f, 0.f};
  int kjr = tid >> 2, kc0 = (tid & 3) * 16;
  for (int jt = 0; jt < LL / 64; ++jt) {
    // prefetch K tile rows and V^T tile rows (both coalesced along inner dim)
    size_t kbase = (size_t)(rowbase + jt * 64 + kjr) * 1024 + 512 + h * DH + kc0;
    s16x8 k0 = *(const s16x8*)(qkh + kbase);
    s16x8 k1 = *(const s16x8*)(qkh + kbase + 8);
    s16x8 k2 = *(const s16x8*)(qkl + kbase);
    s16x8 k3 = *(const s16x8*)(qkl + kbase + 8);
    size_t vgb = (size_t)kjr * LL + jt * 64 + kc0;
    s16x8 v0 = *(const s16x8*)(vbh + vgb);
    s16x8 v1 = *(const s16x8*)(vbh + vgb + 8);
    s16x8 v2 = *(const s16x8*)(vbl + vgb);
    s16x8 v3 = *(const s16x8*)(vbl + vgb + 8);
    __syncthreads();   // prev iter's K/V LDS reads done
    *(s16x8*)&Ks[0][kjr * 72 + kc0]     = k0;
    *(s16x8*)&Ks[0][kjr * 72 + kc0 + 8] = k1;
    *(s16x8*)&Ks[1][kjr * 72 + kc0]     = k2;
    *(s16x8*)&Ks[1][kjr * 72 + kc0 + 8] = k3;
    *(s16x8*)&Vs[0][kjr * 72 + kc0]     = v0;
    *(s16x8*)&Vs[0][kjr * 72 + kc0 + 8] = v1;
    *(s16x8*)&Vs[1][kjr * 72 + kc0]     = v2;
    *(s16x8*)&Vs[1][kjr * 72 + kc0 + 8] = v3;
    __syncthreads();
    // QK^T (q pre-scaled by 0.125 at the qkv epilogue)
    f32x4 s[4];
#pragma unroll
    for (int t = 0; t < 4; ++t) s[t] = (f32x4){0.f, 0.f, 0.f, 0.f};
#pragma unroll
    for (int ks = 0; ks < 2; ++ks) {
#pragma unroll
      for (int t = 0; t < 4; ++t) {
        s16x8 kh_ = *(const s16x8*)&Ks[0][(t * 16 + fr) * 72 + ks * 32 + fk];
        s16x8 kl_ = *(const s16x8*)&Ks[1][(t * 16 + fr) * 72 + ks * 32 + fk];
        s[t] = MFMA(qfh[ks], kh_, s[t]);
        s[t] = MFMA(qfh[ks], kl_, s[t]);
        s[t] = MFMA(qfl[ks], kh_, s[t]);
      }
    }
    // online softmax
#pragma unroll
    for (int r = 0; r < 4; ++r) {
      float s0 = s[0][r], s1 = s[1][r], s2 = s[2][r], s3 = s[3][r];
      float mr = fmaxf(fmaxf(s0, s1), fmaxf(s2, s3));
      mr = fmaxf(mr, __shfl_xor(mr, 1, 64));
      mr = fmaxf(mr, __shfl_xor(mr, 2, 64));
      mr = fmaxf(mr, __shfl_xor(mr, 4, 64));
      mr = fmaxf(mr, __shfl_xor(mr, 8, 64));
      float mn = fmaxf(m_i[r], mr);
      float al = expf(m_i[r] - mn);
      float p0 = expf(s0 - mn), p1 = expf(s1 - mn);
      float p2 = expf(s2 - mn), p3 = expf(s3 - mn);
      float ps = p0 + p1 + p2 + p3;
      ps += __shfl_xor(ps, 1, 64); ps += __shfl_xor(ps, 2, 64);
      ps += __shfl_xor(ps, 4, 64); ps += __shfl_xor(ps, 8, 64);
      l_i[r] = l_i[r] * al + ps;
      m_i[r] = mn;
      oac[0][r] *= al; oac[1][r] *= al; oac[2][r] *= al; oac[3][r] *= al;
      int prow = (w * 16 + fq * 4 + r) * 72;
      short hh_, ll_;
      split_bf16(p0, hh_, ll_); Ps[0][prow + fr]      = hh_; Ps[1][prow + fr]      = ll_;
      split_bf16(p1, hh_, ll_); Ps[0][prow + 16 + fr] = hh_; Ps[1][prow + 16 + fr] = ll_;
      split_bf16(p2, hh_, ll_); Ps[0][prow + 32 + fr] = hh_; Ps[1][prow + 32 + fr] = ll_;
      split_bf16(p3, hh_, ll_); Ps[0][prow + 48 + fr] = hh_; Ps[1][prow + 48 + fr] = ll_;
    }
    // PV (Ps rows are wave-local: same-wave DS ordering, no barrier)
#pragma unroll
    for (int ks = 0; ks < 2; ++ks) {
      s16x8 ph_ = *(const s16x8*)&Ps[0][(w * 16 + fr) * 72 + ks * 32 + fk];
      s16x8 pl_ = *(const s16x8*)&Ps[1][(w * 16 + fr) * 72 + ks * 32 + fk];
#pragma unroll
      for (int t = 0; t < 4; ++t) {
        s16x8 vh_ = *(const s16x8*)&Vs[0][(t * 16 + fr) * 72 + ks * 32 + fk];
        s16x8 vl_ = *(const s16x8*)&Vs[1][(t * 16 + fr) * 72 + ks * 32 + fk];
        oac[t] = MFMA(ph_, vh_, oac[t]);
        oac[t] = MFMA(ph_, vl_, oac[t]);
        oac[t] = MFMA(pl_, vh_, oac[t]);
      }
    }
  }
#pragma unroll
  for (int r = 0; r < 4; ++r) {
    float inv = 1.0f / l_i[r];
    size_t row = rowbase + it * 64 + w * 16 + fq * 4 + r;
#pragma unroll
    for (int t = 0; t < 4; ++t) {
      float v = oac[t][r] * inv;
      short hh_, ll_; split_bf16(v, hh_, ll_);
      size_t off = row * DM + h * DH + t * 16 + fr;
      oh[off] = hh_; ol[off] = ll_;
    }
  }
}

// ---------------- max-pool over sequence (two stage) ----------------
__global__ __launch_bounds__(256) void poolmax1_kernel(const float* __restrict__ x,
                                                       float* __restrict__ partial) {
  int ch = blockIdx.x, b = blockIdx.y, tid = threadIdx.x;
  const float* p = x + ((size_t)b * LL + ch * 128) * DM;
  float m0 = -INFINITY, m1 = -INFINITY;
#pragma unroll 4
  for (int l = 0; l < 128; ++l) {
    m0 = fmaxf(m0, p[(size_t)l * DM + tid]);
    m1 = fmaxf(m1, p[(size_t)l * DM + tid + 256]);
  }
  partial[(size_t)(b * TO + ch) * DM + tid] = m0;
  partial[(size_t)(b * TO + ch) * DM + tid + 256] = m1;
}

__global__ __launch_bounds__(256) void poolmax2_kernel(const float* __restrict__ partial,
                                                       float* __restrict__ pooled) {
  int idx = blockIdx.x * 256 + threadIdx.x;
  int b = idx >> 9, d = idx & 511;
  float m = -INFINITY;
#pragma unroll
  for (int c = 0; c < TO; ++c) m = fmaxf(m, partial[(size_t)(b * TO + c) * DM + d]);
  pooled[idx] = m;
}

// ---------------- head MLP ----------------
__global__ __launch_bounds__(256) void head1_kernel(const float* __restrict__ lnp,
                                                    const float* __restrict__ w,
                                                    const float* __restrict__ bb,
                                                    float* __restrict__ hid) {
  int idx = blockIdx.x * 256 + threadIdx.x;
  int b = idx >> 10, n = idx & 1023;
  const float* xr = lnp + (size_t)b * DM;
  const float* wr = w + (size_t)n * DM;
  float s = 0.f;
  for (int k = 0; k < DM; k += 4) {
    float4 xv = *(const float4*)(xr + k);
    float4 wv = *(const float4*)(wr + k);
    s += xv.x * wv.x + xv.y * wv.y + xv.z * wv.z + xv.w * wv.w;
  }
  hid[idx] = gelu_f(s + bb[n]);
}

__global__ __launch_bounds__(128) void head2_kernel(const float* __restrict__ hid,
                                                    const float* __restrict__ w,
                                                    const float* __restrict__ bb,
                                                    float* __restrict__ dout) {
  int t = threadIdx.x;
  if (t < BN_ * NC) {
    int b = t / NC, n = t - b * NC;
    const float* xr = hid + (size_t)b * MLPD;
    const float* wr = w + (size_t)n * MLPD;
    float s = 0.f;
    for (int k = 0; k < MLPD; k += 4) {
      float4 xv = *(const float4*)(xr + k);
      float4 wv = *(const float4*)(wr + k);
      s += xv.x * wv.x + xv.y * wv.y + xv.z * wv.z + xv.w * wv.w;
    }
    dout[OUT_LOGITS + t] = s + bb[n];
  }
}

// ---------------- launch ----------------
extern "C" void kernel_launch(void* const* d_in, const int* in_sizes, int n_in,
                              void* d_out, int out_size, void* d_ws, size_t ws_size,
                              hipStream_t stream) {
  (void)in_sizes; (void)n_in; (void)out_size; (void)ws_size;
  const float* xyzs     = (const float*)d_in[0];
  const float* oldf     = (const float*)d_in[1];
  const float* conv_d_w = (const float*)d_in[2];
  const float* conv_f_w = (const float*)d_in[3];
  const float* pos_w    = (const float*)d_in[4];
  const float* pos_b    = (const float*)d_in[5];
  const float* contr_w  = (const float*)d_in[6];
  const float* contr_b  = (const float*)d_in[7];
  const float* ln1_s    = (const float*)d_in[8];
  const float* ln1_b    = (const float*)d_in[9];
  const float* qkv_w    = (const float*)d_in[10];
  const float* out_w    = (const float*)d_in[11];
  const float* out_b    = (const float*)d_in[12];
  const float* ln2_s    = (const float*)d_in[13];
  const float* ln2_b    = (const float*)d_in[14];
  const float* ff1_w    = (const float*)d_in[15];
  const float* ff1_b    = (const float*)d_in[16];
  const float* ff2_w    = (const float*)d_in[17];
  const float* ff2_b    = (const float*)d_in[18];
  const float* hl_s     = (const float*)d_in[19];
  const float* hl_b     = (const float*)d_in[20];
  const float* h1_w     = (const float*)d_in[21];
  const float* h1_b     = (const float*)d_in[22];
  const float* h2_w     = (const float*)d_in[23];
  const float* h2_b     = (const float*)d_in[24];
  float* dout = (float*)d_out;
  char* base = (char*)d_ws;
  auto alloc = [&](size_t bytes) { char* p = base; base += (bytes + 255) & ~(size_t)255; return p; };

  float* anchor = (float*)alloc((size_t)BN_ * TO * MM * 3 * 4);
  float* x      = (float*)alloc((size_t)BL * DM * 4);
  short* qkvh   = (short*)alloc((size_t)BL * 1024 * 2);   // q|k packed, stride 1024
  short* qkvl   = (short*)alloc((size_t)BL * 1024 * 2);
  short* vTh    = (short*)alloc((size_t)BN_ * NH * DH * LL * 2);
  short* vTl    = (short*)alloc((size_t)BN_ * NH * DH * LL * 2);
  short* atnh   = (short*)alloc((size_t)BL * DM * 2);
  short* atnl   = (short*)alloc((size_t)BL * DM * 2);
  short* hh     = (short*)alloc((size_t)BL * DM * 2);
  short* hl     = (short*)alloc((size_t)BL * DM * 2);
  short* wsh    = (short*)alloc((size_t)WTOT * 2);
  short* wsl    = (short*)alloc((size_t)WTOT * 2);
  float* partial= (float*)alloc((size_t)BN_ * TO * DM * 4);
  float* pooled = (float*)alloc((size_t)BN_ * DM * 4);
  float* lnp    = (float*)alloc((size_t)BN_ * DM * 4);
  float* hid    = (float*)alloc((size_t)BN_ * MLPD * 4);
  short* fh = qkvh;  // FF hidden aliases qkv (BL*1024 shorts, consumed by then)
  short* fl = qkvl;

  splitw_kernel<<<WTOT / 256, 256, 0, stream>>>(qkv_w, out_w, ff1_w, ff2_w, wsh, wsl);
  fps_kernel<<<BN_ * TO, 256, 0, stream>>>(xyzs, anchor);
  ballconv_kernel<<<BN_ * TO * MM, 64, 0, stream>>>(xyzs, oldf, anchor, conv_d_w, conv_f_w, dout);
  posx_kernel<<<(BL * DM) / 256, 256, 0, stream>>>(anchor, pos_w, pos_b, contr_w, contr_b, dout, x);

  for (int l = 0; l < 4; ++l) {
    ln_split_kernel<<<BL, 64, 0, stream>>>(x, ln1_s + l * DM, ln1_b + l * DM, hh, hl);
    mgemm_kernel<1><<<dim3(1536 / 128, BL / 128), 256, 0, stream>>>(
        hh, hl, wsh + WQOFF + (size_t)l * 786432, wsl + WQOFF + (size_t)l * 786432,
        nullptr, nullptr, nullptr, qkvh, qkvl, vTh, vTl, BL, 1536, DM);
    mattn_kernel<<<dim3(LL / 64, BN_ * NH), 256, 0, stream>>>(qkvh, qkvl, vTh, vTl, atnh, atnl);
    mgemm_kernel<3><<<dim3(DM / 128, BL / 128), 256, 0, stream>>>(
        atnh, atnl, wsh + WOOFF + (size_t)l * 262144, wsl + WOOFF + (size_t)l * 262144,
        out_b + l * DM, x, x, nullptr, nullptr, nullptr, nullptr, BL, DM, DM);
    ln_split_kernel<<<BL, 64, 0, stream>>>(x, ln2_s + l * DM, ln2_b + l * DM, hh, hl);
    mgemm_kernel<2><<<dim3(MLPD / 128, BL / 128), 256, 0, stream>>>(
        hh, hl, wsh + WF1OFF + (size_t)l * 524288, wsl + WF1OFF + (size_t)l * 524288,
        ff1_b + l * MLPD, nullptr, nullptr, fh, fl, nullptr, nullptr, BL, MLPD, DM);
    mgemm_kernel<3><<<dim3(DM / 128, BL / 128), 256, 0, stream>>>(
        fh, fl, wsh + WF2OFF + (size_t)l * 524288, wsl + WF2OFF + (size_t)l * 524288,
        ff2_b + l * DM, x, x, nullptr, nullptr, nullptr, nullptr, BL, DM, MLPD);
  }

  poolmax1_kernel<<<dim3(TO, BN_), 256, 0, stream>>>(x, partial);
  poolmax2_kernel<<<(BN_ * DM) / 256, 256, 0, stream>>>(partial, pooled);
  ln_kernel<<<BN_, 64, 0, stream>>>(pooled, hl_s, hl_b, lnp);
  head1_kernel<<<(BN_ * MLPD) / 256, 256, 0, stream>>>(lnp, h1_w, h1_b, hid);
  head2_kernel<<<1, 128, 0, stream>>>(hid, h2_w, h2_b, dout);
}

// Round 6
// 1591.090 us; speedup vs baseline: 1.1038x; 1.0298x over previous
//
#include <hip/hip_runtime.h>
#include <math.h>

// ---------------- problem constants ----------------
#define BN_  4
#define TT   24
#define NN   4096
#define TO   12
#define MM   128
#define LL   (TO*MM)          // 1536
#define BL   (BN_*LL)         // 6144
#define DM   512
#define NH   8
#define DH   64
#define MLPD 1024
#define NC   30

// output layout (floats): logits | contrastive | features
#define OUT_LOGITS 0
#define OUT_CONTR  (BN_*NC)                 // 120
#define OUT_FEATS  (OUT_CONTR + BL*DM)      // 120 + 3145728

// weight-split region offsets (in shorts)
#define NWQ   3145728   // 4*1536*512
#define NWO   1048576   // 4*512*512
#define NWF1  2097152   // 4*1024*512
#define NWF2  2097152   // 4*512*1024
#define WQOFF   0
#define WOOFF   (NWQ)
#define WF1OFF  (NWQ+NWO)
#define WF2OFF  (NWQ+NWO+NWF1)
#define WTOT    (NWQ+NWO+NWF1+NWF2)   // 8388608

typedef __attribute__((ext_vector_type(8))) short s16x8;
typedef __attribute__((ext_vector_type(4))) float f32x4;
#define MFMA(a,b,c) __builtin_amdgcn_mfma_f32_16x16x32_bf16(a,b,c,0,0,0)

// split fp32 -> bf16 hi (truncate) + bf16 lo (truncated residual); a ~= hi + lo
__device__ __forceinline__ void split_bf16(float a, short &h, short &l) {
  unsigned u = __float_as_uint(a);
  h = (short)(u >> 16);
  float ah = __uint_as_float(u & 0xffff0000u);
  float al = a - ah;
  l = (short)(__float_as_uint(al) >> 16);
}

// exact (non-FMA-contracted) squared distance, matching XLA's mul+add order
__device__ __forceinline__ float d2_3(float ax, float ay, float az,
                                      float bx, float by, float bz) {
#pragma clang fp contract(off)
  float dx = ax - bx, dy = ay - by, dz = az - bz;
  float dx2 = dx * dx, dy2 = dy * dy, dz2 = dz * dz;
  return (dx2 + dy2) + dz2;
}

__device__ __forceinline__ float gelu_f(float v) {
  return 0.5f * v * (1.0f + erff(v * 0.70710678118654752440f));
}

// ---------------- one-time weight split ----------------
__global__ __launch_bounds__(256) void splitw_kernel(
    const float* __restrict__ qkv_w, const float* __restrict__ out_w,
    const float* __restrict__ ff1_w, const float* __restrict__ ff2_w,
    short* __restrict__ wh, short* __restrict__ wl) {
  int i = blockIdx.x * 256 + threadIdx.x;
  const float* src; int off;
  if (i < WOOFF)        { src = qkv_w; off = i; }
  else if (i < WF1OFF)  { src = out_w; off = i - WOOFF; }
  else if (i < WF2OFF)  { src = ff1_w; off = i - WF1OFF; }
  else                  { src = ff2_w; off = i - WF2OFF; }
  float v = src[off];
  short h, l; split_bf16(v, h, l);
  wh[i] = h; wl[i] = l;
}

// ---------------- FPS v2: one block per (b, ti), 1 barrier/iter ----------------
__global__ __launch_bounds__(256) void fps_kernel(const float* __restrict__ xyzs,
                                                  float* __restrict__ anchor) {
  __shared__ float sx[NN], sy[NN], sz[NN];
  __shared__ unsigned long long skey[2][4];
  int blk = blockIdx.x;
  int b = blk / TO, ti = blk - b * TO;
  const float* src = xyzs + ((size_t)(b * TT + 2 * ti)) * NN * 3;
  int tid = threadIdx.x;
  float dist[16], px[16], py[16], pz[16];
#pragma unroll
  for (int s = 0; s < 16; ++s) {
    int p = tid + s * 256;
    px[s] = src[p * 3 + 0]; py[s] = src[p * 3 + 1]; pz[s] = src[p * 3 + 2];
    sx[p] = px[s]; sy[p] = py[s]; sz[p] = pz[s];
    dist[s] = 1e10f;
  }
  __syncthreads();
  float lx = sx[0], ly = sy[0], lz = sz[0];
  float* aout = anchor + (size_t)blk * MM * 3;
  if (tid == 0) { aout[0] = lx; aout[1] = ly; aout[2] = lz; }
  for (int j = 1; j < MM; ++j) {
    unsigned long long best = 0;
#pragma unroll
    for (int s = 0; s < 16; ++s) {
      float d2 = d2_3(px[s], py[s], pz[s], lx, ly, lz);
      float dn = fminf(dist[s], d2);
      dist[s] = dn;
      unsigned long long key = ((unsigned long long)__float_as_uint(dn) << 12)
                               | (unsigned)(4095 - (tid + s * 256));
      best = key > best ? key : best;
    }
#pragma unroll
    for (int m = 1; m < 64; m <<= 1) {
      unsigned long long o = __shfl_xor(best, m, 64);
      best = o > best ? o : best;
    }
    if ((tid & 63) == 0) skey[j & 1][tid >> 6] = best;
    __syncthreads();
    unsigned long long b0 = skey[j & 1][0], b1 = skey[j & 1][1];
    unsigned long long b2 = skey[j & 1][2], b3 = skey[j & 1][3];
    unsigned long long bb = b0 > b1 ? b0 : b1;
    unsigned long long cc = b2 > b3 ? b2 : b3;
    bb = bb > cc ? bb : cc;
    int bi = 4095 - (int)(bb & 0xFFFull);
    lx = sx[bi]; ly = sy[bi]; lz = sz[bi];
    if (tid == 0) { aout[j * 3 + 0] = lx; aout[j * 3 + 1] = ly; aout[j * 3 + 2] = lz; }
  }
}

// ---------------- ball query + p4dconv + max-pool: one wave per (b,ti,m) ----------------
__global__ __launch_bounds__(64) void ballconv_kernel(
    const float* __restrict__ xyzs, const float* __restrict__ oldf,
    const float* __restrict__ anchor,
    const float* __restrict__ wdw, const float* __restrict__ wfw,
    float* __restrict__ dout) {
  __shared__ int   sidx[32];
  __shared__ float sdisp[32][4];
  __shared__ float sfeat[32][2];
  int blk = blockIdx.x;
  int b = blk / (TO * MM);
  int rem = blk - b * (TO * MM);
  int ti = rem / MM;
  int lane = threadIdx.x;
  const float* ap = anchor + (size_t)blk * 3;
  float ax = ap[0], ay = ap[1], az = ap[2];
  int d0 = lane * 8;
  float4 wd[8]; float2 wf[8];
#pragma unroll
  for (int jd = 0; jd < 8; ++jd) {
    wd[jd] = *(const float4*)(wdw + (d0 + jd) * 4);
    wf[jd] = *(const float2*)(wfw + (d0 + jd) * 2);
  }
  float fmx[8];
#pragma unroll
  for (int jd = 0; jd < 8; ++jd) fmx[jd] = -INFINITY;

  for (int o = -1; o <= 1; ++o) {
    int tp = 1 + 2 * ti + o;
    int orig = (tp == 0) ? 0 : tp - 1;
    const float* nx = xyzs + ((size_t)(b * TT + orig)) * NN * 3;
    const float* nf = oldf + ((size_t)(b * TT + orig)) * 2 * NN;
    int cnt = 0;
    for (int base = 0; base < NN && cnt < 32; base += 64) {
      int p = base + lane;
      float d2 = d2_3(ax, ay, az, nx[p * 3], nx[p * 3 + 1], nx[p * 3 + 2]);
      bool in = d2 < 0.09f;
      unsigned long long mask = __ballot(in);
      int pos = __popcll(mask & ((1ull << lane) - 1ull));
      if (in && (cnt + pos) < 32) sidx[cnt + pos] = p;
      cnt += __popcll(mask);
    }
    __syncthreads();
    int used = cnt < 32 ? cnt : 32;
    if (lane < 32 && lane >= used) sidx[lane] = (used > 0) ? sidx[0] : 0;
    __syncthreads();
    if (lane < 32) {
      int p = sidx[lane];
      sdisp[lane][0] = nx[p * 3 + 0] - ax;
      sdisp[lane][1] = nx[p * 3 + 1] - ay;
      sdisp[lane][2] = nx[p * 3 + 2] - az;
      sdisp[lane][3] = (float)o;
      sfeat[lane][0] = nf[p];
      sfeat[lane][1] = nf[NN + p];
    }
    __syncthreads();
    for (int k = 0; k < 32; ++k) {
      float p0 = sdisp[k][0], p1 = sdisp[k][1], p2 = sdisp[k][2], p3 = sdisp[k][3];
      float f0 = sfeat[k][0], f1 = sfeat[k][1];
#pragma unroll
      for (int jd = 0; jd < 8; ++jd) {
        float de = wd[jd].x * p0 + wd[jd].y * p1 + wd[jd].z * p2 + wd[jd].w * p3;
        float fe = wf[jd].x * f0 + wf[jd].y * f1;
        fmx[jd] = fmaxf(fmx[jd], fe * de);
      }
    }
    __syncthreads();
  }
  float* fout = dout + OUT_FEATS + (size_t)blk * DM + d0;
#pragma unroll
  for (int jd = 0; jd < 8; jd += 4)
    *(float4*)(fout + jd) = make_float4(fmx[jd], fmx[jd + 1], fmx[jd + 2], fmx[jd + 3]);
}

// ---------------- pos/contrastive embed + x = relu(pos + features) ----------------
__global__ __launch_bounds__(256) void posx_kernel(
    const float* __restrict__ anchor,
    const float* __restrict__ pw, const float* __restrict__ pb,
    const float* __restrict__ cw, const float* __restrict__ cb,
    float* __restrict__ dout, float* __restrict__ x) {
  int idx = blockIdx.x * 256 + threadIdx.x;
  int bl = idx >> 9, d = idx & 511;
  int ti = (bl % LL) / MM;
  const float* ap = anchor + (size_t)bl * 3;
  float c0 = ap[0], c1 = ap[1], c2 = ap[2], c3 = (float)(ti + 1);
  float4 pwv = *(const float4*)(pw + d * 4);
  float4 cwv = *(const float4*)(cw + d * 4);
  float pos = pwv.x * c0 + pwv.y * c1 + pwv.z * c2 + pwv.w * c3 + pb[d];
  float con = cwv.x * c0 + cwv.y * c1 + cwv.z * c2 + cwv.w * c3 + cb[d];
  dout[OUT_CONTR + (size_t)idx] = con;
  float v = pos + dout[OUT_FEATS + (size_t)idx];
  x[idx] = v > 0.0f ? v : 0.0f;
}

// ---------------- LayerNorm -> split bf16 hi/lo: one wave per row ----------------
__global__ __launch_bounds__(64) void ln_split_kernel(
    const float* __restrict__ x, const float* __restrict__ gs,
    const float* __restrict__ gb, short* __restrict__ oh, short* __restrict__ ol) {
  int row = blockIdx.x, lane = threadIdx.x;
  const float* xr = x + (size_t)row * DM + lane * 8;
  float4 v0 = *(const float4*)xr;
  float4 v1 = *(const float4*)(xr + 4);
  float v[8] = {v0.x, v0.y, v0.z, v0.w, v1.x, v1.y, v1.z, v1.w};
  float s = 0.f;
#pragma unroll
  for (int j = 0; j < 8; ++j) s += v[j];
  for (int m = 1; m < 64; m <<= 1) s += __shfl_xor(s, m, 64);
  float mu = s * (1.0f / DM);
  float d[8], ss = 0.f;
#pragma unroll
  for (int j = 0; j < 8; ++j) { d[j] = v[j] - mu; ss += d[j] * d[j]; }
  for (int m = 1; m < 64; m <<= 1) ss += __shfl_xor(ss, m, 64);
  float rs = 1.0f / sqrtf(ss * (1.0f / DM) + 1e-5f);
  const float* gsr = gs + lane * 8;
  const float* gbr = gb + lane * 8;
  s16x8 hv, lv;
#pragma unroll
  for (int j = 0; j < 8; ++j) {
    float f = d[j] * rs * gsr[j] + gbr[j];
    short h, l; split_bf16(f, h, l);
    hv[j] = h; lv[j] = l;
  }
  *(s16x8*)(oh + (size_t)row * DM + lane * 8) = hv;
  *(s16x8*)(ol + (size_t)row * DM + lane * 8) = lv;
}

// ---------------- LayerNorm fp32 out (head path) ----------------
__global__ __launch_bounds__(64) void ln_kernel(
    const float* __restrict__ x, const float* __restrict__ gs,
    const float* __restrict__ gb, float* __restrict__ out) {
  int row = blockIdx.x, lane = threadIdx.x;
  const float* xr = x + (size_t)row * DM + lane * 8;
  float4 v0 = *(const float4*)xr;
  float4 v1 = *(const float4*)(xr + 4);
  float v[8] = {v0.x, v0.y, v0.z, v0.w, v1.x, v1.y, v1.z, v1.w};
  float s = 0.f;
#pragma unroll
  for (int j = 0; j < 8; ++j) s += v[j];
  for (int m = 1; m < 64; m <<= 1) s += __shfl_xor(s, m, 64);
  float mu = s * (1.0f / DM);
  float d[8], ss = 0.f;
#pragma unroll
  for (int j = 0; j < 8; ++j) { d[j] = v[j] - mu; ss += d[j] * d[j]; }
  for (int m = 1; m < 64; m <<= 1) ss += __shfl_xor(ss, m, 64);
  float rs = 1.0f / sqrtf(ss * (1.0f / DM) + 1e-5f);
  const float* gsr = gs + lane * 8;
  const float* gbr = gb + lane * 8;
  float* orow = out + (size_t)row * DM + lane * 8;
  float r[8];
#pragma unroll
  for (int j = 0; j < 8; ++j) r[j] = d[j] * rs * gsr[j] + gbr[j];
  *(float4*)orow       = make_float4(r[0], r[1], r[2], r[3]);
  *(float4*)(orow + 4) = make_float4(r[4], r[5], r[6], r[7]);
}

// ---------------- split-bf16 MFMA GEMM 128x128 (pre-split A and W) ----------------
// EPI: 1 = qkv (q scaled by 0.125, q,k -> Ch/Cl stride 1024; v -> vT transposed),
//      2 = bias+gelu+split-out, 3 = bias+residual fp32 out
template <int EPI>
__global__ __launch_bounds__(256) void mgemm_kernel(
    const short* __restrict__ Ah, const short* __restrict__ Al,
    const short* __restrict__ Wh, const short* __restrict__ Wl,
    const float* __restrict__ bias, const float* __restrict__ res,
    float* __restrict__ Cf, short* __restrict__ Ch, short* __restrict__ Cl,
    short* __restrict__ vTh, short* __restrict__ vTl,
    int M, int N, int K) {
  __shared__ short As[2][128 * 40];   // [hi/lo][row][k(32)+pad8]
  __shared__ short Ws[2][128 * 40];
  int tid = threadIdx.x;
  int lane = tid & 63, w = tid >> 6;
  int wr = w >> 1, wc = w & 1;
  int row0 = blockIdx.y * 128, col0 = blockIdx.x * 128;
  int srow = tid >> 1, skc = (tid & 1) * 16;
  const short* Ahp = Ah + (size_t)(row0 + srow) * K + skc;
  const short* Alp = Al + (size_t)(row0 + srow) * K + skc;
  const short* Whp = Wh + (size_t)(col0 + srow) * K + skc;
  const short* Wlp = Wl + (size_t)(col0 + srow) * K + skc;
  int fr = lane & 15, fk = (lane >> 4) * 8;
  f32x4 acc[16];
#pragma unroll
  for (int i = 0; i < 16; ++i) acc[i] = (f32x4){0.f, 0.f, 0.f, 0.f};
  s16x8 rA0 = *(const s16x8*)(Ahp);
  s16x8 rA1 = *(const s16x8*)(Ahp + 8);
  s16x8 rA2 = *(const s16x8*)(Alp);
  s16x8 rA3 = *(const s16x8*)(Alp + 8);
  s16x8 rW0 = *(const s16x8*)(Whp);
  s16x8 rW1 = *(const s16x8*)(Whp + 8);
  s16x8 rW2 = *(const s16x8*)(Wlp);
  s16x8 rW3 = *(const s16x8*)(Wlp + 8);
  for (int ks = 0; ks < K; ks += 32) {
    __syncthreads();
    *(s16x8*)&As[0][srow * 40 + skc]     = rA0;
    *(s16x8*)&As[0][srow * 40 + skc + 8] = rA1;
    *(s16x8*)&As[1][srow * 40 + skc]     = rA2;
    *(s16x8*)&As[1][srow * 40 + skc + 8] = rA3;
    *(s16x8*)&Ws[0][srow * 40 + skc]     = rW0;
    *(s16x8*)&Ws[0][srow * 40 + skc + 8] = rW1;
    *(s16x8*)&Ws[1][srow * 40 + skc]     = rW2;
    *(s16x8*)&Ws[1][srow * 40 + skc + 8] = rW3;
    __syncthreads();
    if (ks + 32 < K) {
      rA0 = *(const s16x8*)(Ahp + ks + 32);
      rA1 = *(const s16x8*)(Ahp + ks + 40);
      rA2 = *(const s16x8*)(Alp + ks + 32);
      rA3 = *(const s16x8*)(Alp + ks + 40);
      rW0 = *(const s16x8*)(Whp + ks + 32);
      rW1 = *(const s16x8*)(Whp + ks + 40);
      rW2 = *(const s16x8*)(Wlp + ks + 32);
      rW3 = *(const s16x8*)(Wlp + ks + 40);
    }
    s16x8 bh_[4], bl_[4];
#pragma unroll
    for (int t = 0; t < 4; ++t) {
      bh_[t] = *(const s16x8*)&Ws[0][(wc * 64 + t * 16 + fr) * 40 + fk];
      bl_[t] = *(const s16x8*)&Ws[1][(wc * 64 + t * 16 + fr) * 40 + fk];
    }
#pragma unroll
    for (int a = 0; a < 4; ++a) {
      s16x8 ah_ = *(const s16x8*)&As[0][(wr * 64 + a * 16 + fr) * 40 + fk];
      s16x8 al_ = *(const s16x8*)&As[1][(wr * 64 + a * 16 + fr) * 40 + fk];
#pragma unroll
      for (int t = 0; t < 4; ++t) {
        f32x4 c = acc[a * 4 + t];
        c = MFMA(ah_, bh_[t], c);
        c = MFMA(ah_, bl_[t], c);
        c = MFMA(al_, bh_[t], c);
        acc[a * 4 + t] = c;
      }
    }
  }
  int fq = lane >> 4;
  if (EPI == 1) {
    int bidx = row0 / LL;
    int j0 = row0 - bidx * LL + wr * 64;
    float qscale = (col0 < 512) ? 0.125f : 1.0f;  // exact pow2: commutes with split
#pragma unroll
    for (int a = 0; a < 4; ++a) {
#pragma unroll
      for (int t = 0; t < 4; ++t) {
        int c = col0 + wc * 64 + t * 16 + fr;
        f32x4 v = acc[a * 4 + t];
        if (col0 < 1024) {  // q,k -> row-major stride 1024
#pragma unroll
          for (int r = 0; r < 4; ++r) {
            int row = row0 + wr * 64 + a * 16 + fq * 4 + r;
            size_t off = (size_t)row * 1024 + c;
            short h, l; split_bf16(v[r] * qscale, h, l);
            Ch[off] = h; Cl[off] = l;
          }
        } else {            // v -> transposed [(b*8+h)*64+d][LL], 4 rows packed per store
          int vcol = c - 1024;
          size_t vidx = ((size_t)(bidx * 8 + (vcol >> 6)) * 64 + (vcol & 63)) * LL
                        + j0 + a * 16 + fq * 4;
          short4 hv, lv;
          short h, l;
          split_bf16(v[0], h, l); hv.x = h; lv.x = l;
          split_bf16(v[1], h, l); hv.y = h; lv.y = l;
          split_bf16(v[2], h, l); hv.z = h; lv.z = l;
          split_bf16(v[3], h, l); hv.w = h; lv.w = l;
          *(short4*)(vTh + vidx) = hv;
          *(short4*)(vTl + vidx) = lv;
        }
      }
    }
  } else {
#pragma unroll
    for (int a = 0; a < 4; ++a) {
#pragma unroll
      for (int t = 0; t < 4; ++t) {
#pragma unroll
        for (int r = 0; r < 4; ++r) {
          int row = row0 + wr * 64 + a * 16 + fq * 4 + r;
          int c   = col0 + wc * 64 + t * 16 + fr;
          size_t off = (size_t)row * N + c;
          float v = acc[a * 4 + t][r] + bias[c];
          if (EPI == 2) {
            v = gelu_f(v);
            short h, l; split_bf16(v, h, l);
            Ch[off] = h; Cl[off] = l;
          } else {
            Cf[off] = v + res[off];
          }
        }
      }
    }
  }
}

// ---------------- split-bf16 MFMA flash attention v6 ----------------
// 128 q-rows/block, 8 waves (512 thr); XCD-aware 1D grid: n&31 = bh, n>>5 = it
// (same-bh blocks share an XCD's L2 for K/V). K + V^T staged in LDS, 2 barriers/jt;
// P round-trips wave-local LDS (no barrier). q pre-scaled by 0.125.
__global__ __launch_bounds__(512) void mattn_kernel(
    const short* __restrict__ qkh, const short* __restrict__ qkl,
    const short* __restrict__ vTh, const short* __restrict__ vTl,
    short* __restrict__ oh, short* __restrict__ ol) {
  __shared__ short Ks[2][64 * 72];
  __shared__ short Vs[2][64 * 72];
  __shared__ short Ps[2][128 * 72];
  int n = blockIdx.x;
  int bh = n & 31, it = n >> 5;
  int b = bh >> 3, h = bh & 7;
  int tid = threadIdx.x, lane = tid & 63, w = tid >> 6;  // w in 0..7
  int fr = lane & 15, fq = lane >> 4, fk = fq * 8;
  size_t rowbase = (size_t)b * LL;
  s16x8 qfh[2], qfl[2];
  {
    size_t qoff = (size_t)(rowbase + it * 128 + w * 16 + fr) * 1024 + h * DH;
    qfh[0] = *(const s16x8*)(qkh + qoff + fk);
    qfh[1] = *(const s16x8*)(qkh + qoff + 32 + fk);
    qfl[0] = *(const s16x8*)(qkl + qoff + fk);
    qfl[1] = *(const s16x8*)(qkl + qoff + 32 + fk);
  }
  const short* vbh = vTh + (size_t)(b * 8 + h) * 64 * LL;
  const short* vbl = vTl + (size_t)(b * 8 + h) * 64 * LL;
  float m_i[4], l_i[4];
  f32x4 oac[4];
#pragma unroll
  for (int r = 0; r < 4; ++r) { m_i[r] = -INFINITY; l_i[r] = 0.f; }
#pragma unroll
  for (int t = 0; t < 4; ++t) oac[t] = (f32x4){0.f, 0.f, 0.f, 0.f};
  int sr = tid >> 3, sc = (tid & 7) * 8;   // staging: row 0..63, col 0,8,..,56
  for (int jt = 0; jt < LL / 64; ++jt) {
    // prefetch K rows (row-major) and V^T rows (d-major), one 16B per thread per buffer
    size_t kbase = (size_t)(rowbase + jt * 64 + sr) * 1024 + 512 + h * DH + sc;
    s16x8 k0 = *(const s16x8*)(qkh + kbase);
    s16x8 k1 = *(const s16x8*)(qkl + kbase);
    size_t vgb = (size_t)sr * LL + jt * 64 + sc;
    s16x8 v0 = *(const s16x8*)(vbh + vgb);
    s16x8 v1 = *(const s16x8*)(vbl + vgb);
    __syncthreads();   // prev iter's K/V LDS reads done
    *(s16x8*)&Ks[0][sr * 72 + sc] = k0;
    *(s16x8*)&Ks[1][sr * 72 + sc] = k1;
    *(s16x8*)&Vs[0][sr * 72 + sc] = v0;
    *(s16x8*)&Vs[1][sr * 72 + sc] = v1;
    __syncthreads();
    // QK^T (q pre-scaled by 0.125 at the qkv epilogue)
    f32x4 s[4];
#pragma unroll
    for (int t = 0; t < 4; ++t) s[t] = (f32x4){0.f, 0.f, 0.f, 0.f};
#pragma unroll
    for (int ks = 0; ks < 2; ++ks) {
#pragma unroll
      for (int t = 0; t < 4; ++t) {
        s16x8 kh_ = *(const s16x8*)&Ks[0][(t * 16 + fr) * 72 + ks * 32 + fk];
        s16x8 kl_ = *(const s16x8*)&Ks[1][(t * 16 + fr) * 72 + ks * 32 + fk];
        s[t] = MFMA(qfh[ks], kh_, s[t]);
        s[t] = MFMA(qfh[ks], kl_, s[t]);
        s[t] = MFMA(qfl[ks], kh_, s[t]);
      }
    }
    // online softmax
#pragma unroll
    for (int r = 0; r < 4; ++r) {
      float s0 = s[0][r], s1 = s[1][r], s2 = s[2][r], s3 = s[3][r];
      float mr = fmaxf(fmaxf(s0, s1), fmaxf(s2, s3));
      mr = fmaxf(mr, __shfl_xor(mr, 1, 64));
      mr = fmaxf(mr, __shfl_xor(mr, 2, 64));
      mr = fmaxf(mr, __shfl_xor(mr, 4, 64));
      mr = fmaxf(mr, __shfl_xor(mr, 8, 64));
      float mn = fmaxf(m_i[r], mr);
      float al = expf(m_i[r] - mn);
      float p0 = expf(s0 - mn), p1 = expf(s1 - mn);
      float p2 = expf(s2 - mn), p3 = expf(s3 - mn);
      float ps = p0 + p1 + p2 + p3;
      ps += __shfl_xor(ps, 1, 64); ps += __shfl_xor(ps, 2, 64);
      ps += __shfl_xor(ps, 4, 64); ps += __shfl_xor(ps, 8, 64);
      l_i[r] = l_i[r] * al + ps;
      m_i[r] = mn;
      oac[0][r] *= al; oac[1][r] *= al; oac[2][r] *= al; oac[3][r] *= al;
      int prow = (w * 16 + fq * 4 + r) * 72;
      short hh_, ll_;
      split_bf16(p0, hh_, ll_); Ps[0][prow + fr]      = hh_; Ps[1][prow + fr]      = ll_;
      split_bf16(p1, hh_, ll_); Ps[0][prow + 16 + fr] = hh_; Ps[1][prow + 16 + fr] = ll_;
      split_bf16(p2, hh_, ll_); Ps[0][prow + 32 + fr] = hh_; Ps[1][prow + 32 + fr] = ll_;
      split_bf16(p3, hh_, ll_); Ps[0][prow + 48 + fr] = hh_; Ps[1][prow + 48 + fr] = ll_;
    }
    // PV (Ps rows are wave-exclusive: same-wave DS ordering, no barrier)
#pragma unroll
    for (int ks = 0; ks < 2; ++ks) {
      s16x8 ph_ = *(const s16x8*)&Ps[0][(w * 16 + fr) * 72 + ks * 32 + fk];
      s16x8 pl_ = *(const s16x8*)&Ps[1][(w * 16 + fr) * 72 + ks * 32 + fk];
#pragma unroll
      for (int t = 0; t < 4; ++t) {
        s16x8 vh_ = *(const s16x8*)&Vs[0][(t * 16 + fr) * 72 + ks * 32 + fk];
        s16x8 vl_ = *(const s16x8*)&Vs[1][(t * 16 + fr) * 72 + ks * 32 + fk];
        oac[t] = MFMA(ph_, vh_, oac[t]);
        oac[t] = MFMA(ph_, vl_, oac[t]);
        oac[t] = MFMA(pl_, vh_, oac[t]);
      }
    }
  }
#pragma unroll
  for (int r = 0; r < 4; ++r) {
    float inv = 1.0f / l_i[r];
    size_t row = rowbase + it * 128 + w * 16 + fq * 4 + r;
#pragma unroll
    for (int t = 0; t < 4; ++t) {
      float v = oac[t][r] * inv;
      short hh_, ll_; split_bf16(v, hh_, ll_);
      size_t off = row * DM + h * DH + t * 16 + fr;
      oh[off] = hh_; ol[off] = ll_;
    }
  }
}

// ---------------- max-pool over sequence (two stage) ----------------
__global__ __launch_bounds__(256) void poolmax1_kernel(const float* __restrict__ x,
                                                       float* __restrict__ partial) {
  int ch = blockIdx.x, b = blockIdx.y, tid = threadIdx.x;
  const float* p = x + ((size_t)b * LL + ch * 128) * DM;
  float m0 = -INFINITY, m1 = -INFINITY;
#pragma unroll 4
  for (int l = 0; l < 128; ++l) {
    m0 = fmaxf(m0, p[(size_t)l * DM + tid]);
    m1 = fmaxf(m1, p[(size_t)l * DM + tid + 256]);
  }
  partial[(size_t)(b * TO + ch) * DM + tid] = m0;
  partial[(size_t)(b * TO + ch) * DM + tid + 256] = m1;
}

__global__ __launch_bounds__(256) void poolmax2_kernel(const float* __restrict__ partial,
                                                       float* __restrict__ pooled) {
  int idx = blockIdx.x * 256 + threadIdx.x;
  int b = idx >> 9, d = idx & 511;
  float m = -INFINITY;
#pragma unroll
  for (int c = 0; c < TO; ++c) m = fmaxf(m, partial[(size_t)(b * TO + c) * DM + d]);
  pooled[idx] = m;
}

// ---------------- head MLP ----------------
__global__ __launch_bounds__(256) void head1_kernel(const float* __restrict__ lnp,
                                                    const float* __restrict__ w,
                                                    const float* __restrict__ bb,
                                                    float* __restrict__ hid) {
  int idx = blockIdx.x * 256 + threadIdx.x;
  int b = idx >> 10, n = idx & 1023;
  const float* xr = lnp + (size_t)b * DM;
  const float* wr = w + (size_t)n * DM;
  float s = 0.f;
  for (int k = 0; k < DM; k += 4) {
    float4 xv = *(const float4*)(xr + k);
    float4 wv = *(const float4*)(wr + k);
    s += xv.x * wv.x + xv.y * wv.y + xv.z * wv.z + xv.w * wv.w;
  }
  hid[idx] = gelu_f(s + bb[n]);
}

__global__ __launch_bounds__(128) void head2_kernel(const float* __restrict__ hid,
                                                    const float* __restrict__ w,
                                                    const float* __restrict__ bb,
                                                    float* __restrict__ dout) {
  int t = threadIdx.x;
  if (t < BN_ * NC) {
    int b = t / NC, n = t - b * NC;
    const float* xr = hid + (size_t)b * MLPD;
    const float* wr = w + (size_t)n * MLPD;
    float s = 0.f;
    for (int k = 0; k < MLPD; k += 4) {
      float4 xv = *(const float4*)(xr + k);
      float4 wv = *(const float4*)(wr + k);
      s += xv.x * wv.x + xv.y * wv.y + xv.z * wv.z + xv.w * wv.w;
    }
    dout[OUT_LOGITS + t] = s + bb[n];
  }
}

// ---------------- launch ----------------
extern "C" void kernel_launch(void* const* d_in, const int* in_sizes, int n_in,
                              void* d_out, int out_size, void* d_ws, size_t ws_size,
                              hipStream_t stream) {
  (void)in_sizes; (void)n_in; (void)out_size; (void)ws_size;
  const float* xyzs     = (const float*)d_in[0];
  const float* oldf     = (const float*)d_in[1];
  const float* conv_d_w = (const float*)d_in[2];
  const float* conv_f_w = (const float*)d_in[3];
  const float* pos_w    = (const float*)d_in[4];
  const float* pos_b    = (const float*)d_in[5];
  const float* contr_w  = (const float*)d_in[6];
  const float* contr_b  = (const float*)d_in[7];
  const float* ln1_s    = (const float*)d_in[8];
  const float* ln1_b    = (const float*)d_in[9];
  const float* qkv_w    = (const float*)d_in[10];
  const float* out_w    = (const float*)d_in[11];
  const float* out_b    = (const float*)d_in[12];
  const float* ln2_s    = (const float*)d_in[13];
  const float* ln2_b    = (const float*)d_in[14];
  const float* ff1_w    = (const float*)d_in[15];
  const float* ff1_b    = (const float*)d_in[16];
  const float* ff2_w    = (const float*)d_in[17];
  const float* ff2_b    = (const float*)d_in[18];
  const float* hl_s     = (const float*)d_in[19];
  const float* hl_b     = (const float*)d_in[20];
  const float* h1_w     = (const float*)d_in[21];
  const float* h1_b     = (const float*)d_in[22];
  const float* h2_w     = (const float*)d_in[23];
  const float* h2_b     = (const float*)d_in[24];
  float* dout = (float*)d_out;
  char* base = (char*)d_ws;
  auto alloc = [&](size_t bytes) { char* p = base; base += (bytes + 255) & ~(size_t)255; return p; };

  float* anchor = (float*)alloc((size_t)BN_ * TO * MM * 3 * 4);
  float* x      = (float*)alloc((size_t)BL * DM * 4);
  short* qkvh   = (short*)alloc((size_t)BL * 1024 * 2);   // q|k packed, stride 1024
  short* qkvl   = (short*)alloc((size_t)BL * 1024 * 2);
  short* vTh    = (short*)alloc((size_t)BN_ * NH * DH * LL * 2);
  short* vTl    = (short*)alloc((size_t)BN_ * NH * DH * LL * 2);
  short* atnh   = (short*)alloc((size_t)BL * DM * 2);
  short* atnl   = (short*)alloc((size_t)BL * DM * 2);
  short* hh     = (short*)alloc((size_t)BL * DM * 2);
  short* hl     = (short*)alloc((size_t)BL * DM * 2);
  short* wsh    = (short*)alloc((size_t)WTOT * 2);
  short* wsl    = (short*)alloc((size_t)WTOT * 2);
  float* partial= (float*)alloc((size_t)BN_ * TO * DM * 4);
  float* pooled = (float*)alloc((size_t)BN_ * DM * 4);
  float* lnp    = (float*)alloc((size_t)BN_ * DM * 4);
  float* hid    = (float*)alloc((size_t)BN_ * MLPD * 4);
  short* fh = qkvh;  // FF hidden aliases qkv (BL*1024 shorts, consumed by then)
  short* fl = qkvl;

  splitw_kernel<<<WTOT / 256, 256, 0, stream>>>(qkv_w, out_w, ff1_w, ff2_w, wsh, wsl);
  fps_kernel<<<BN_ * TO, 256, 0, stream>>>(xyzs, anchor);
  ballconv_kernel<<<BN_ * TO * MM, 64, 0, stream>>>(xyzs, oldf, anchor, conv_d_w, conv_f_w, dout);
  posx_kernel<<<(BL * DM) / 256, 256, 0, stream>>>(anchor, pos_w, pos_b, contr_w, contr_b, dout, x);

  for (int l = 0; l < 4; ++l) {
    ln_split_kernel<<<BL, 64, 0, stream>>>(x, ln1_s + l * DM, ln1_b + l * DM, hh, hl);
    mgemm_kernel<1><<<dim3(1536 / 128, BL / 128), 256, 0, stream>>>(
        hh, hl, wsh + WQOFF + (size_t)l * 786432, wsl + WQOFF + (size_t)l * 786432,
        nullptr, nullptr, nullptr, qkvh, qkvl, vTh, vTl, BL, 1536, DM);
    mattn_kernel<<<dim3((LL / 128) * 32), 512, 0, stream>>>(qkvh, qkvl, vTh, vTl, atnh, atnl);
    mgemm_kernel<3><<<dim3(DM / 128, BL / 128), 256, 0, stream>>>(
        atnh, atnl, wsh + WOOFF + (size_t)l * 262144, wsl + WOOFF + (size_t)l * 262144,
        out_b + l * DM, x, x, nullptr, nullptr, nullptr, nullptr, BL, DM, DM);
    ln_split_kernel<<<BL, 64, 0, stream>>>(x, ln2_s + l * DM, ln2_b + l * DM, hh, hl);
    mgemm_kernel<2><<<dim3(MLPD / 128, BL / 128), 256, 0, stream>>>(
        hh, hl, wsh + WF1OFF + (size_t)l * 524288, wsl + WF1OFF + (size_t)l * 524288,
        ff1_b + l * MLPD, nullptr, nullptr, fh, fl, nullptr, nullptr, BL, MLPD, DM);
    mgemm_kernel<3><<<dim3(DM / 128, BL / 128), 256, 0, stream>>>(
        fh, fl, wsh + WF2OFF + (size_t)l * 524288, wsl + WF2OFF + (size_t)l * 524288,
        ff2_b + l * DM, x, x, nullptr, nullptr, nullptr, nullptr, BL, DM, MLPD);
  }

  poolmax1_kernel<<<dim3(TO, BN_), 256, 0, stream>>>(x, partial);
  poolmax2_kernel<<<(BN_ * DM) / 256, 256, 0, stream>>>(partial, pooled);
  ln_kernel<<<BN_, 64, 0, stream>>>(pooled, hl_s, hl_b, lnp);
  head1_kernel<<<(BN_ * MLPD) / 256, 256, 0, stream>>>(lnp, h1_w, h1_b, hid);
  head2_kernel<<<1, 128, 0, stream>>>(hid, h2_w, h2_b, dout);
}

// Round 7
// 1478.550 us; speedup vs baseline: 1.1878x; 1.0761x over previous
//
#include <hip/hip_runtime.h>
#include <math.h>

// ---------------- problem constants ----------------
#define BN_  4
#define TT   24
#define NN   4096
#define TO   12
#define MM   128
#define LL   (TO*MM)          // 1536
#define BL   (BN_*LL)         // 6144
#define DM   512
#define NH   8
#define DH   64
#define MLPD 1024
#define NC   30

// output layout (floats): logits | contrastive | features
#define OUT_LOGITS 0
#define OUT_CONTR  (BN_*NC)                 // 120
#define OUT_FEATS  (OUT_CONTR + BL*DM)      // 120 + 3145728

// weight-split region offsets (in shorts)
#define NWQ   3145728   // 4*1536*512
#define NWO   1048576   // 4*512*512
#define NWF1  2097152   // 4*1024*512
#define NWF2  2097152   // 4*512*1024
#define WQOFF   0
#define WOOFF   (NWQ)
#define WF1OFF  (NWQ+NWO)
#define WF2OFF  (NWQ+NWO+NWF1)
#define WTOT    (NWQ+NWO+NWF1+NWF2)   // 8388608

typedef __attribute__((ext_vector_type(8))) short s16x8;
typedef __attribute__((ext_vector_type(4))) float f32x4;
#define MFMA(a,b,c) __builtin_amdgcn_mfma_f32_16x16x32_bf16(a,b,c,0,0,0)

// split fp32 -> bf16 hi (truncate) + bf16 lo (truncated residual); a ~= hi + lo
__device__ __forceinline__ void split_bf16(float a, short &h, short &l) {
  unsigned u = __float_as_uint(a);
  h = (short)(u >> 16);
  float ah = __uint_as_float(u & 0xffff0000u);
  float al = a - ah;
  l = (short)(__float_as_uint(al) >> 16);
}

// exact (non-FMA-contracted) squared distance, matching XLA's mul+add order
__device__ __forceinline__ float d2_3(float ax, float ay, float az,
                                      float bx, float by, float bz) {
#pragma clang fp contract(off)
  float dx = ax - bx, dy = ay - by, dz = az - bz;
  float dx2 = dx * dx, dy2 = dy * dy, dz2 = dz * dz;
  return (dx2 + dy2) + dz2;
}

__device__ __forceinline__ float gelu_f(float v) {
  return 0.5f * v * (1.0f + erff(v * 0.70710678118654752440f));
}

// ---------------- one-time weight split ----------------
__global__ __launch_bounds__(256) void splitw_kernel(
    const float* __restrict__ qkv_w, const float* __restrict__ out_w,
    const float* __restrict__ ff1_w, const float* __restrict__ ff2_w,
    short* __restrict__ wh, short* __restrict__ wl) {
  int i = blockIdx.x * 256 + threadIdx.x;
  const float* src; int off;
  if (i < WOOFF)        { src = qkv_w; off = i; }
  else if (i < WF1OFF)  { src = out_w; off = i - WOOFF; }
  else if (i < WF2OFF)  { src = ff1_w; off = i - WF1OFF; }
  else                  { src = ff2_w; off = i - WF2OFF; }
  float v = src[off];
  short h, l; split_bf16(v, h, l);
  wh[i] = h; wl[i] = l;
}

// ---------------- FPS v2: one block per (b, ti), 1 barrier/iter ----------------
__global__ __launch_bounds__(256) void fps_kernel(const float* __restrict__ xyzs,
                                                  float* __restrict__ anchor) {
  __shared__ float sx[NN], sy[NN], sz[NN];
  __shared__ unsigned long long skey[2][4];
  int blk = blockIdx.x;
  int b = blk / TO, ti = blk - b * TO;
  const float* src = xyzs + ((size_t)(b * TT + 2 * ti)) * NN * 3;
  int tid = threadIdx.x;
  float dist[16], px[16], py[16], pz[16];
#pragma unroll
  for (int s = 0; s < 16; ++s) {
    int p = tid + s * 256;
    px[s] = src[p * 3 + 0]; py[s] = src[p * 3 + 1]; pz[s] = src[p * 3 + 2];
    sx[p] = px[s]; sy[p] = py[s]; sz[p] = pz[s];
    dist[s] = 1e10f;
  }
  __syncthreads();
  float lx = sx[0], ly = sy[0], lz = sz[0];
  float* aout = anchor + (size_t)blk * MM * 3;
  if (tid == 0) { aout[0] = lx; aout[1] = ly; aout[2] = lz; }
  for (int j = 1; j < MM; ++j) {
    unsigned long long best = 0;
#pragma unroll
    for (int s = 0; s < 16; ++s) {
      float d2 = d2_3(px[s], py[s], pz[s], lx, ly, lz);
      float dn = fminf(dist[s], d2);
      dist[s] = dn;
      unsigned long long key = ((unsigned long long)__float_as_uint(dn) << 12)
                               | (unsigned)(4095 - (tid + s * 256));
      best = key > best ? key : best;
    }
#pragma unroll
    for (int m = 1; m < 64; m <<= 1) {
      unsigned long long o = __shfl_xor(best, m, 64);
      best = o > best ? o : best;
    }
    if ((tid & 63) == 0) skey[j & 1][tid >> 6] = best;
    __syncthreads();
    unsigned long long b0 = skey[j & 1][0], b1 = skey[j & 1][1];
    unsigned long long b2 = skey[j & 1][2], b3 = skey[j & 1][3];
    unsigned long long bb = b0 > b1 ? b0 : b1;
    unsigned long long cc = b2 > b3 ? b2 : b3;
    bb = bb > cc ? bb : cc;
    int bi = 4095 - (int)(bb & 0xFFFull);
    lx = sx[bi]; ly = sy[bi]; lz = sz[bi];
    if (tid == 0) { aout[j * 3 + 0] = lx; aout[j * 3 + 1] = ly; aout[j * 3 + 2] = lz; }
  }
}

// ---------------- ball query + p4dconv + max-pool: one wave per (b,ti,m) ----------------
__global__ __launch_bounds__(64) void ballconv_kernel(
    const float* __restrict__ xyzs, const float* __restrict__ oldf,
    const float* __restrict__ anchor,
    const float* __restrict__ wdw, const float* __restrict__ wfw,
    float* __restrict__ dout) {
  __shared__ int   sidx[32];
  __shared__ float sdisp[32][4];
  __shared__ float sfeat[32][2];
  int blk = blockIdx.x;
  int b = blk / (TO * MM);
  int rem = blk - b * (TO * MM);
  int ti = rem / MM;
  int lane = threadIdx.x;
  const float* ap = anchor + (size_t)blk * 3;
  float ax = ap[0], ay = ap[1], az = ap[2];
  int d0 = lane * 8;
  float4 wd[8]; float2 wf[8];
#pragma unroll
  for (int jd = 0; jd < 8; ++jd) {
    wd[jd] = *(const float4*)(wdw + (d0 + jd) * 4);
    wf[jd] = *(const float2*)(wfw + (d0 + jd) * 2);
  }
  float fmx[8];
#pragma unroll
  for (int jd = 0; jd < 8; ++jd) fmx[jd] = -INFINITY;

  for (int o = -1; o <= 1; ++o) {
    int tp = 1 + 2 * ti + o;
    int orig = (tp == 0) ? 0 : tp - 1;
    const float* nx = xyzs + ((size_t)(b * TT + orig)) * NN * 3;
    const float* nf = oldf + ((size_t)(b * TT + orig)) * 2 * NN;
    int cnt = 0;
    for (int base = 0; base < NN && cnt < 32; base += 64) {
      int p = base + lane;
      float d2 = d2_3(ax, ay, az, nx[p * 3], nx[p * 3 + 1], nx[p * 3 + 2]);
      bool in = d2 < 0.09f;
      unsigned long long mask = __ballot(in);
      int pos = __popcll(mask & ((1ull << lane) - 1ull));
      if (in && (cnt + pos) < 32) sidx[cnt + pos] = p;
      cnt += __popcll(mask);
    }
    __syncthreads();
    int used = cnt < 32 ? cnt : 32;
    if (lane < 32 && lane >= used) sidx[lane] = (used > 0) ? sidx[0] : 0;
    __syncthreads();
    if (lane < 32) {
      int p = sidx[lane];
      sdisp[lane][0] = nx[p * 3 + 0] - ax;
      sdisp[lane][1] = nx[p * 3 + 1] - ay;
      sdisp[lane][2] = nx[p * 3 + 2] - az;
      sdisp[lane][3] = (float)o;
      sfeat[lane][0] = nf[p];
      sfeat[lane][1] = nf[NN + p];
    }
    __syncthreads();
    for (int k = 0; k < 32; ++k) {
      float p0 = sdisp[k][0], p1 = sdisp[k][1], p2 = sdisp[k][2], p3 = sdisp[k][3];
      float f0 = sfeat[k][0], f1 = sfeat[k][1];
#pragma unroll
      for (int jd = 0; jd < 8; ++jd) {
        float de = wd[jd].x * p0 + wd[jd].y * p1 + wd[jd].z * p2 + wd[jd].w * p3;
        float fe = wf[jd].x * f0 + wf[jd].y * f1;
        fmx[jd] = fmaxf(fmx[jd], fe * de);
      }
    }
    __syncthreads();
  }
  float* fout = dout + OUT_FEATS + (size_t)blk * DM + d0;
#pragma unroll
  for (int jd = 0; jd < 8; jd += 4)
    *(float4*)(fout + jd) = make_float4(fmx[jd], fmx[jd + 1], fmx[jd + 2], fmx[jd + 3]);
}

// ---------------- pos/contrastive embed + x = relu(pos + features) ----------------
__global__ __launch_bounds__(256) void posx_kernel(
    const float* __restrict__ anchor,
    const float* __restrict__ pw, const float* __restrict__ pb,
    const float* __restrict__ cw, const float* __restrict__ cb,
    float* __restrict__ dout, float* __restrict__ x) {
  int idx = blockIdx.x * 256 + threadIdx.x;
  int bl = idx >> 9, d = idx & 511;
  int ti = (bl % LL) / MM;
  const float* ap = anchor + (size_t)bl * 3;
  float c0 = ap[0], c1 = ap[1], c2 = ap[2], c3 = (float)(ti + 1);
  float4 pwv = *(const float4*)(pw + d * 4);
  float4 cwv = *(const float4*)(cw + d * 4);
  float pos = pwv.x * c0 + pwv.y * c1 + pwv.z * c2 + pwv.w * c3 + pb[d];
  float con = cwv.x * c0 + cwv.y * c1 + cwv.z * c2 + cwv.w * c3 + cb[d];
  dout[OUT_CONTR + (size_t)idx] = con;
  float v = pos + dout[OUT_FEATS + (size_t)idx];
  x[idx] = v > 0.0f ? v : 0.0f;
}

// ---------------- LayerNorm -> split bf16 hi/lo: one wave per row ----------------
__global__ __launch_bounds__(64) void ln_split_kernel(
    const float* __restrict__ x, const float* __restrict__ gs,
    const float* __restrict__ gb, short* __restrict__ oh, short* __restrict__ ol) {
  int row = blockIdx.x, lane = threadIdx.x;
  const float* xr = x + (size_t)row * DM + lane * 8;
  float4 v0 = *(const float4*)xr;
  float4 v1 = *(const float4*)(xr + 4);
  float v[8] = {v0.x, v0.y, v0.z, v0.w, v1.x, v1.y, v1.z, v1.w};
  float s = 0.f;
#pragma unroll
  for (int j = 0; j < 8; ++j) s += v[j];
  for (int m = 1; m < 64; m <<= 1) s += __shfl_xor(s, m, 64);
  float mu = s * (1.0f / DM);
  float d[8], ss = 0.f;
#pragma unroll
  for (int j = 0; j < 8; ++j) { d[j] = v[j] - mu; ss += d[j] * d[j]; }
  for (int m = 1; m < 64; m <<= 1) ss += __shfl_xor(ss, m, 64);
  float rs = 1.0f / sqrtf(ss * (1.0f / DM) + 1e-5f);
  const float* gsr = gs + lane * 8;
  const float* gbr = gb + lane * 8;
  s16x8 hv, lv;
#pragma unroll
  for (int j = 0; j < 8; ++j) {
    float f = d[j] * rs * gsr[j] + gbr[j];
    short h, l; split_bf16(f, h, l);
    hv[j] = h; lv[j] = l;
  }
  *(s16x8*)(oh + (size_t)row * DM + lane * 8) = hv;
  *(s16x8*)(ol + (size_t)row * DM + lane * 8) = lv;
}

// ---------------- LayerNorm fp32 out (head path) ----------------
__global__ __launch_bounds__(64) void ln_kernel(
    const float* __restrict__ x, const float* __restrict__ gs,
    const float* __restrict__ gb, float* __restrict__ out) {
  int row = blockIdx.x, lane = threadIdx.x;
  const float* xr = x + (size_t)row * DM + lane * 8;
  float4 v0 = *(const float4*)xr;
  float4 v1 = *(const float4*)(xr + 4);
  float v[8] = {v0.x, v0.y, v0.z, v0.w, v1.x, v1.y, v1.z, v1.w};
  float s = 0.f;
#pragma unroll
  for (int j = 0; j < 8; ++j) s += v[j];
  for (int m = 1; m < 64; m <<= 1) s += __shfl_xor(s, m, 64);
  float mu = s * (1.0f / DM);
  float d[8], ss = 0.f;
#pragma unroll
  for (int j = 0; j < 8; ++j) { d[j] = v[j] - mu; ss += d[j] * d[j]; }
  for (int m = 1; m < 64; m <<= 1) ss += __shfl_xor(ss, m, 64);
  float rs = 1.0f / sqrtf(ss * (1.0f / DM) + 1e-5f);
  const float* gsr = gs + lane * 8;
  const float* gbr = gb + lane * 8;
  float* orow = out + (size_t)row * DM + lane * 8;
  float r[8];
#pragma unroll
  for (int j = 0; j < 8; ++j) r[j] = d[j] * rs * gsr[j] + gbr[j];
  *(float4*)orow       = make_float4(r[0], r[1], r[2], r[3]);
  *(float4*)(orow + 4) = make_float4(r[4], r[5], r[6], r[7]);
}

// ---------------- split-bf16 MFMA GEMM 128x128 (pre-split A and W) ----------------
// EPI: 1 = qkv (q scaled by 0.125, q,k -> Ch/Cl stride 1024; v -> vT transposed),
//      2 = bias+gelu+split-out, 3 = bias+residual fp32 out
template <int EPI>
__global__ __launch_bounds__(256) void mgemm_kernel(
    const short* __restrict__ Ah, const short* __restrict__ Al,
    const short* __restrict__ Wh, const short* __restrict__ Wl,
    const float* __restrict__ bias, const float* __restrict__ res,
    float* __restrict__ Cf, short* __restrict__ Ch, short* __restrict__ Cl,
    short* __restrict__ vTh, short* __restrict__ vTl,
    int M, int N, int K) {
  __shared__ short As[2][128 * 40];   // [hi/lo][row][k(32)+pad8]
  __shared__ short Ws[2][128 * 40];
  int tid = threadIdx.x;
  int lane = tid & 63, w = tid >> 6;
  int wr = w >> 1, wc = w & 1;
  int row0 = blockIdx.y * 128, col0 = blockIdx.x * 128;
  int srow = tid >> 1, skc = (tid & 1) * 16;
  const short* Ahp = Ah + (size_t)(row0 + srow) * K + skc;
  const short* Alp = Al + (size_t)(row0 + srow) * K + skc;
  const short* Whp = Wh + (size_t)(col0 + srow) * K + skc;
  const short* Wlp = Wl + (size_t)(col0 + srow) * K + skc;
  int fr = lane & 15, fk = (lane >> 4) * 8;
  f32x4 acc[16];
#pragma unroll
  for (int i = 0; i < 16; ++i) acc[i] = (f32x4){0.f, 0.f, 0.f, 0.f};
  s16x8 rA0 = *(const s16x8*)(Ahp);
  s16x8 rA1 = *(const s16x8*)(Ahp + 8);
  s16x8 rA2 = *(const s16x8*)(Alp);
  s16x8 rA3 = *(const s16x8*)(Alp + 8);
  s16x8 rW0 = *(const s16x8*)(Whp);
  s16x8 rW1 = *(const s16x8*)(Whp + 8);
  s16x8 rW2 = *(const s16x8*)(Wlp);
  s16x8 rW3 = *(const s16x8*)(Wlp + 8);
  for (int ks = 0; ks < K; ks += 32) {
    __syncthreads();
    *(s16x8*)&As[0][srow * 40 + skc]     = rA0;
    *(s16x8*)&As[0][srow * 40 + skc + 8] = rA1;
    *(s16x8*)&As[1][srow * 40 + skc]     = rA2;
    *(s16x8*)&As[1][srow * 40 + skc + 8] = rA3;
    *(s16x8*)&Ws[0][srow * 40 + skc]     = rW0;
    *(s16x8*)&Ws[0][srow * 40 + skc + 8] = rW1;
    *(s16x8*)&Ws[1][srow * 40 + skc]     = rW2;
    *(s16x8*)&Ws[1][srow * 40 + skc + 8] = rW3;
    __syncthreads();
    if (ks + 32 < K) {
      rA0 = *(const s16x8*)(Ahp + ks + 32);
      rA1 = *(const s16x8*)(Ahp + ks + 40);
      rA2 = *(const s16x8*)(Alp + ks + 32);
      rA3 = *(const s16x8*)(Alp + ks + 40);
      rW0 = *(const s16x8*)(Whp + ks + 32);
      rW1 = *(const s16x8*)(Whp + ks + 40);
      rW2 = *(const s16x8*)(Wlp + ks + 32);
      rW3 = *(const s16x8*)(Wlp + ks + 40);
    }
    s16x8 bh_[4], bl_[4];
#pragma unroll
    for (int t = 0; t < 4; ++t) {
      bh_[t] = *(const s16x8*)&Ws[0][(wc * 64 + t * 16 + fr) * 40 + fk];
      bl_[t] = *(const s16x8*)&Ws[1][(wc * 64 + t * 16 + fr) * 40 + fk];
    }
#pragma unroll
    for (int a = 0; a < 4; ++a) {
      s16x8 ah_ = *(const s16x8*)&As[0][(wr * 64 + a * 16 + fr) * 40 + fk];
      s16x8 al_ = *(const s16x8*)&As[1][(wr * 64 + a * 16 + fr) * 40 + fk];
#pragma unroll
      for (int t = 0; t < 4; ++t) {
        f32x4 c = acc[a * 4 + t];
        c = MFMA(ah_, bh_[t], c);
        c = MFMA(ah_, bl_[t], c);
        c = MFMA(al_, bh_[t], c);
        acc[a * 4 + t] = c;
      }
    }
  }
  int fq = lane >> 4;
  if (EPI == 1) {
    int bidx = row0 / LL;
    int j0 = row0 - bidx * LL + wr * 64;
    float qscale = (col0 < 512) ? 0.125f : 1.0f;  // exact pow2: commutes with split
#pragma unroll
    for (int a = 0; a < 4; ++a) {
#pragma unroll
      for (int t = 0; t < 4; ++t) {
        int c = col0 + wc * 64 + t * 16 + fr;
        f32x4 v = acc[a * 4 + t];
        if (col0 < 1024) {  // q,k -> row-major stride 1024
#pragma unroll
          for (int r = 0; r < 4; ++r) {
            int row = row0 + wr * 64 + a * 16 + fq * 4 + r;
            size_t off = (size_t)row * 1024 + c;
            short h, l; split_bf16(v[r] * qscale, h, l);
            Ch[off] = h; Cl[off] = l;
          }
        } else {            // v -> transposed [(b*8+h)*64+d][LL], 4 rows packed per store
          int vcol = c - 1024;
          size_t vidx = ((size_t)(bidx * 8 + (vcol >> 6)) * 64 + (vcol & 63)) * LL
                        + j0 + a * 16 + fq * 4;
          short4 hv, lv;
          short h, l;
          split_bf16(v[0], h, l); hv.x = h; lv.x = l;
          split_bf16(v[1], h, l); hv.y = h; lv.y = l;
          split_bf16(v[2], h, l); hv.z = h; lv.z = l;
          split_bf16(v[3], h, l); hv.w = h; lv.w = l;
          *(short4*)(vTh + vidx) = hv;
          *(short4*)(vTl + vidx) = lv;
        }
      }
    }
  } else {
#pragma unroll
    for (int a = 0; a < 4; ++a) {
#pragma unroll
      for (int t = 0; t < 4; ++t) {
#pragma unroll
        for (int r = 0; r < 4; ++r) {
          int row = row0 + wr * 64 + a * 16 + fq * 4 + r;
          int c   = col0 + wc * 64 + t * 16 + fr;
          size_t off = (size_t)row * N + c;
          float v = acc[a * 4 + t][r] + bias[c];
          if (EPI == 2) {
            v = gelu_f(v);
            short h, l; split_bf16(v, h, l);
            Ch[off] = h; Cl[off] = l;
          } else {
            Cf[off] = v + res[off];
          }
        }
      }
    }
  }
}

// ---------------- split-bf16 MFMA flash attention v7 ----------------
// v6 geometry (128 q-rows, 8 waves, XCD-aware grid) + VALU cuts:
// __expf (native v_exp) and l-accumulation on the MATRIX pipe via B=ones MFMA
// (l obeys the same recurrence as O: l = l*alpha + P.1).
__global__ __launch_bounds__(512) void mattn_kernel(
    const short* __restrict__ qkh, const short* __restrict__ qkl,
    const short* __restrict__ vTh, const short* __restrict__ vTl,
    short* __restrict__ oh, short* __restrict__ ol) {
  __shared__ short Ks[2][64 * 72];
  __shared__ short Vs[2][64 * 72];
  __shared__ short Ps[2][128 * 72];
  int n = blockIdx.x;
  int bh = n & 31, it = n >> 5;
  int b = bh >> 3, h = bh & 7;
  int tid = threadIdx.x, lane = tid & 63, w = tid >> 6;  // w in 0..7
  int fr = lane & 15, fq = lane >> 4, fk = fq * 8;
  size_t rowbase = (size_t)b * LL;
  s16x8 qfh[2], qfl[2];
  {
    size_t qoff = (size_t)(rowbase + it * 128 + w * 16 + fr) * 1024 + h * DH;
    qfh[0] = *(const s16x8*)(qkh + qoff + fk);
    qfh[1] = *(const s16x8*)(qkh + qoff + 32 + fk);
    qfl[0] = *(const s16x8*)(qkl + qoff + fk);
    qfl[1] = *(const s16x8*)(qkl + qoff + 32 + fk);
  }
  s16x8 ones;
#pragma unroll
  for (int j = 0; j < 8; ++j) ones[j] = (short)0x3F80;   // bf16 1.0
  const short* vbh = vTh + (size_t)(b * 8 + h) * 64 * LL;
  const short* vbl = vTl + (size_t)(b * 8 + h) * 64 * LL;
  float m_i[4];
  f32x4 oac[4], lsacc;
#pragma unroll
  for (int r = 0; r < 4; ++r) m_i[r] = -INFINITY;
  lsacc = (f32x4){0.f, 0.f, 0.f, 0.f};
#pragma unroll
  for (int t = 0; t < 4; ++t) oac[t] = (f32x4){0.f, 0.f, 0.f, 0.f};
  int sr = tid >> 3, sc = (tid & 7) * 8;   // staging: row 0..63, col 0,8,..,56
  for (int jt = 0; jt < LL / 64; ++jt) {
    // prefetch K rows (row-major) and V^T rows (d-major), one 16B per thread per buffer
    size_t kbase = (size_t)(rowbase + jt * 64 + sr) * 1024 + 512 + h * DH + sc;
    s16x8 k0 = *(const s16x8*)(qkh + kbase);
    s16x8 k1 = *(const s16x8*)(qkl + kbase);
    size_t vgb = (size_t)sr * LL + jt * 64 + sc;
    s16x8 v0 = *(const s16x8*)(vbh + vgb);
    s16x8 v1 = *(const s16x8*)(vbl + vgb);
    __syncthreads();   // prev iter's K/V LDS reads done
    *(s16x8*)&Ks[0][sr * 72 + sc] = k0;
    *(s16x8*)&Ks[1][sr * 72 + sc] = k1;
    *(s16x8*)&Vs[0][sr * 72 + sc] = v0;
    *(s16x8*)&Vs[1][sr * 72 + sc] = v1;
    __syncthreads();
    // QK^T (q pre-scaled by 0.125 at the qkv epilogue)
    f32x4 s[4];
#pragma unroll
    for (int t = 0; t < 4; ++t) s[t] = (f32x4){0.f, 0.f, 0.f, 0.f};
#pragma unroll
    for (int ks = 0; ks < 2; ++ks) {
#pragma unroll
      for (int t = 0; t < 4; ++t) {
        s16x8 kh_ = *(const s16x8*)&Ks[0][(t * 16 + fr) * 72 + ks * 32 + fk];
        s16x8 kl_ = *(const s16x8*)&Ks[1][(t * 16 + fr) * 72 + ks * 32 + fk];
        s[t] = MFMA(qfh[ks], kh_, s[t]);
        s[t] = MFMA(qfh[ks], kl_, s[t]);
        s[t] = MFMA(qfl[ks], kh_, s[t]);
      }
    }
    // online softmax (max via shuffles; sums accumulated on the matrix pipe below)
#pragma unroll
    for (int r = 0; r < 4; ++r) {
      float s0 = s[0][r], s1 = s[1][r], s2 = s[2][r], s3 = s[3][r];
      float mr = fmaxf(fmaxf(s0, s1), fmaxf(s2, s3));
      mr = fmaxf(mr, __shfl_xor(mr, 1, 64));
      mr = fmaxf(mr, __shfl_xor(mr, 2, 64));
      mr = fmaxf(mr, __shfl_xor(mr, 4, 64));
      mr = fmaxf(mr, __shfl_xor(mr, 8, 64));
      float mn = fmaxf(m_i[r], mr);
      float al = __expf(m_i[r] - mn);
      float p0 = __expf(s0 - mn), p1 = __expf(s1 - mn);
      float p2 = __expf(s2 - mn), p3 = __expf(s3 - mn);
      m_i[r] = mn;
      lsacc[r] *= al;
      oac[0][r] *= al; oac[1][r] *= al; oac[2][r] *= al; oac[3][r] *= al;
      int prow = (w * 16 + fq * 4 + r) * 72;
      short hh_, ll_;
      split_bf16(p0, hh_, ll_); Ps[0][prow + fr]      = hh_; Ps[1][prow + fr]      = ll_;
      split_bf16(p1, hh_, ll_); Ps[0][prow + 16 + fr] = hh_; Ps[1][prow + 16 + fr] = ll_;
      split_bf16(p2, hh_, ll_); Ps[0][prow + 32 + fr] = hh_; Ps[1][prow + 32 + fr] = ll_;
      split_bf16(p3, hh_, ll_); Ps[0][prow + 48 + fr] = hh_; Ps[1][prow + 48 + fr] = ll_;
    }
    // PV + row-sum (Ps rows are wave-exclusive: same-wave DS ordering, no barrier)
#pragma unroll
    for (int ks = 0; ks < 2; ++ks) {
      s16x8 ph_ = *(const s16x8*)&Ps[0][(w * 16 + fr) * 72 + ks * 32 + fk];
      s16x8 pl_ = *(const s16x8*)&Ps[1][(w * 16 + fr) * 72 + ks * 32 + fk];
#pragma unroll
      for (int t = 0; t < 4; ++t) {
        s16x8 vh_ = *(const s16x8*)&Vs[0][(t * 16 + fr) * 72 + ks * 32 + fk];
        s16x8 vl_ = *(const s16x8*)&Vs[1][(t * 16 + fr) * 72 + ks * 32 + fk];
        oac[t] = MFMA(ph_, vh_, oac[t]);
        oac[t] = MFMA(ph_, vl_, oac[t]);
        oac[t] = MFMA(pl_, vh_, oac[t]);
      }
      lsacc = MFMA(ph_, ones, lsacc);
      lsacc = MFMA(pl_, ones, lsacc);
    }
  }
#pragma unroll
  for (int r = 0; r < 4; ++r) {
    float inv = 1.0f / lsacc[r];
    size_t row = rowbase + it * 128 + w * 16 + fq * 4 + r;
#pragma unroll
    for (int t = 0; t < 4; ++t) {
      float v = oac[t][r] * inv;
      short hh_, ll_; split_bf16(v, hh_, ll_);
      size_t off = row * DM + h * DH + t * 16 + fr;
      oh[off] = hh_; ol[off] = ll_;
    }
  }
}

// ---------------- max-pool over sequence (two stage) ----------------
__global__ __launch_bounds__(256) void poolmax1_kernel(const float* __restrict__ x,
                                                       float* __restrict__ partial) {
  int ch = blockIdx.x, b = blockIdx.y, tid = threadIdx.x;
  const float* p = x + ((size_t)b * LL + ch * 128) * DM;
  float m0 = -INFINITY, m1 = -INFINITY;
#pragma unroll 4
  for (int l = 0; l < 128; ++l) {
    m0 = fmaxf(m0, p[(size_t)l * DM + tid]);
    m1 = fmaxf(m1, p[(size_t)l * DM + tid + 256]);
  }
  partial[(size_t)(b * TO + ch) * DM + tid] = m0;
  partial[(size_t)(b * TO + ch) * DM + tid + 256] = m1;
}

__global__ __launch_bounds__(256) void poolmax2_kernel(const float* __restrict__ partial,
                                                       float* __restrict__ pooled) {
  int idx = blockIdx.x * 256 + threadIdx.x;
  int b = idx >> 9, d = idx & 511;
  float m = -INFINITY;
#pragma unroll
  for (int c = 0; c < TO; ++c) m = fmaxf(m, partial[(size_t)(b * TO + c) * DM + d]);
  pooled[idx] = m;
}

// ---------------- head MLP ----------------
__global__ __launch_bounds__(256) void head1_kernel(const float* __restrict__ lnp,
                                                    const float* __restrict__ w,
                                                    const float* __restrict__ bb,
                                                    float* __restrict__ hid) {
  int idx = blockIdx.x * 256 + threadIdx.x;
  int b = idx >> 10, n = idx & 1023;
  const float* xr = lnp + (size_t)b * DM;
  const float* wr = w + (size_t)n * DM;
  float s = 0.f;
  for (int k = 0; k < DM; k += 4) {
    float4 xv = *(const float4*)(xr + k);
    float4 wv = *(const float4*)(wr + k);
    s += xv.x * wv.x + xv.y * wv.y + xv.z * wv.z + xv.w * wv.w;
  }
  hid[idx] = gelu_f(s + bb[n]);
}

__global__ __launch_bounds__(128) void head2_kernel(const float* __restrict__ hid,
                                                    const float* __restrict__ w,
                                                    const float* __restrict__ bb,
                                                    float* __restrict__ dout) {
  int t = threadIdx.x;
  if (t < BN_ * NC) {
    int b = t / NC, n = t - b * NC;
    const float* xr = hid + (size_t)b * MLPD;
    const float* wr = w + (size_t)n * MLPD;
    float s = 0.f;
    for (int k = 0; k < MLPD; k += 4) {
      float4 xv = *(const float4*)(xr + k);
      float4 wv = *(const float4*)(wr + k);
      s += xv.x * wv.x + xv.y * wv.y + xv.z * wv.z + xv.w * wv.w;
    }
    dout[OUT_LOGITS + t] = s + bb[n];
  }
}

// ---------------- launch ----------------
extern "C" void kernel_launch(void* const* d_in, const int* in_sizes, int n_in,
                              void* d_out, int out_size, void* d_ws, size_t ws_size,
                              hipStream_t stream) {
  (void)in_sizes; (void)n_in; (void)out_size; (void)ws_size;
  const float* xyzs     = (const float*)d_in[0];
  const float* oldf     = (const float*)d_in[1];
  const float* conv_d_w = (const float*)d_in[2];
  const float* conv_f_w = (const float*)d_in[3];
  const float* pos_w    = (const float*)d_in[4];
  const float* pos_b    = (const float*)d_in[5];
  const float* contr_w  = (const float*)d_in[6];
  const float* contr_b  = (const float*)d_in[7];
  const float* ln1_s    = (const float*)d_in[8];
  const float* ln1_b    = (const float*)d_in[9];
  const float* qkv_w    = (const float*)d_in[10];
  const float* out_w    = (const float*)d_in[11];
  const float* out_b    = (const float*)d_in[12];
  const float* ln2_s    = (const float*)d_in[13];
  const float* ln2_b    = (const float*)d_in[14];
  const float* ff1_w    = (const float*)d_in[15];
  const float* ff1_b    = (const float*)d_in[16];
  const float* ff2_w    = (const float*)d_in[17];
  const float* ff2_b    = (const float*)d_in[18];
  const float* hl_s     = (const float*)d_in[19];
  const float* hl_b     = (const float*)d_in[20];
  const float* h1_w     = (const float*)d_in[21];
  const float* h1_b     = (const float*)d_in[22];
  const float* h2_w     = (const float*)d_in[23];
  const float* h2_b     = (const float*)d_in[24];
  float* dout = (float*)d_out;
  char* base = (char*)d_ws;
  auto alloc = [&](size_t bytes) { char* p = base; base += (bytes + 255) & ~(size_t)255; return p; };

  float* anchor = (float*)alloc((size_t)BN_ * TO * MM * 3 * 4);
  float* x      = (float*)alloc((size_t)BL * DM * 4);
  short* qkvh   = (short*)alloc((size_t)BL * 1024 * 2);   // q|k packed, stride 1024
  short* qkvl   = (short*)alloc((size_t)BL * 1024 * 2);
  short* vTh    = (short*)alloc((size_t)BN_ * NH * DH * LL * 2);
  short* vTl    = (short*)alloc((size_t)BN_ * NH * DH * LL * 2);
  short* atnh   = (short*)alloc((size_t)BL * DM * 2);
  short* atnl   = (short*)alloc((size_t)BL * DM * 2);
  short* hh     = (short*)alloc((size_t)BL * DM * 2);
  short* hl     = (short*)alloc((size_t)BL * DM * 2);
  short* wsh    = (short*)alloc((size_t)WTOT * 2);
  short* wsl    = (short*)alloc((size_t)WTOT * 2);
  float* partial= (float*)alloc((size_t)BN_ * TO * DM * 4);
  float* pooled = (float*)alloc((size_t)BN_ * DM * 4);
  float* lnp    = (float*)alloc((size_t)BN_ * DM * 4);
  float* hid    = (float*)alloc((size_t)BN_ * MLPD * 4);
  short* fh = qkvh;  // FF hidden aliases qkv (BL*1024 shorts, consumed by then)
  short* fl = qkvl;

  splitw_kernel<<<WTOT / 256, 256, 0, stream>>>(qkv_w, out_w, ff1_w, ff2_w, wsh, wsl);
  fps_kernel<<<BN_ * TO, 256, 0, stream>>>(xyzs, anchor);
  ballconv_kernel<<<BN_ * TO * MM, 64, 0, stream>>>(xyzs, oldf, anchor, conv_d_w, conv_f_w, dout);
  posx_kernel<<<(BL * DM) / 256, 256, 0, stream>>>(anchor, pos_w, pos_b, contr_w, contr_b, dout, x);

  for (int l = 0; l < 4; ++l) {
    ln_split_kernel<<<BL, 64, 0, stream>>>(x, ln1_s + l * DM, ln1_b + l * DM, hh, hl);
    mgemm_kernel<1><<<dim3(1536 / 128, BL / 128), 256, 0, stream>>>(
        hh, hl, wsh + WQOFF + (size_t)l * 786432, wsl + WQOFF + (size_t)l * 786432,
        nullptr, nullptr, nullptr, qkvh, qkvl, vTh, vTl, BL, 1536, DM);
    mattn_kernel<<<dim3((LL / 128) * 32), 512, 0, stream>>>(qkvh, qkvl, vTh, vTl, atnh, atnl);
    mgemm_kernel<3><<<dim3(DM / 128, BL / 128), 256, 0, stream>>>(
        atnh, atnl, wsh + WOOFF + (size_t)l * 262144, wsl + WOOFF + (size_t)l * 262144,
        out_b + l * DM, x, x, nullptr, nullptr, nullptr, nullptr, BL, DM, DM);
    ln_split_kernel<<<BL, 64, 0, stream>>>(x, ln2_s + l * DM, ln2_b + l * DM, hh, hl);
    mgemm_kernel<2><<<dim3(MLPD / 128, BL / 128), 256, 0, stream>>>(
        hh, hl, wsh + WF1OFF + (size_t)l * 524288, wsl + WF1OFF + (size_t)l * 524288,
        ff1_b + l * MLPD, nullptr, nullptr, fh, fl, nullptr, nullptr, BL, MLPD, DM);
    mgemm_kernel<3><<<dim3(DM / 128, BL / 128), 256, 0, stream>>>(
        fh, fl, wsh + WF2OFF + (size_t)l * 524288, wsl + WF2OFF + (size_t)l * 524288,
        ff2_b + l * DM, x, x, nullptr, nullptr, nullptr, nullptr, BL, DM, MLPD);
  }

  poolmax1_kernel<<<dim3(TO, BN_), 256, 0, stream>>>(x, partial);
  poolmax2_kernel<<<(BN_ * DM) / 256, 256, 0, stream>>>(partial, pooled);
  ln_kernel<<<BN_, 64, 0, stream>>>(pooled, hl_s, hl_b, lnp);
  head1_kernel<<<(BN_ * MLPD) / 256, 256, 0, stream>>>(lnp, h1_w, h1_b, hid);
  head2_kernel<<<1, 128, 0, stream>>>(hid, h2_w, h2_b, dout);
}

// Round 8
// 1467.106 us; speedup vs baseline: 1.1971x; 1.0078x over previous
//
#include <hip/hip_runtime.h>
#include <math.h>

// ---------------- problem constants ----------------
#define BN_  4
#define TT   24
#define NN   4096
#define TO   12
#define MM   128
#define LL   (TO*MM)          // 1536
#define BL   (BN_*LL)         // 6144
#define DM   512
#define NH   8
#define DH   64
#define MLPD 1024
#define NC   30

// output layout (floats): logits | contrastive | features
#define OUT_LOGITS 0
#define OUT_CONTR  (BN_*NC)                 // 120
#define OUT_FEATS  (OUT_CONTR + BL*DM)      // 120 + 3145728

// weight-split region offsets (in shorts)
#define NWQ   3145728   // 4*1536*512
#define NWO   1048576   // 4*512*512
#define NWF1  2097152   // 4*1024*512
#define NWF2  2097152   // 4*512*1024
#define WQOFF   0
#define WOOFF   (NWQ)
#define WF1OFF  (NWQ+NWO)
#define WF2OFF  (NWQ+NWO+NWF1)
#define WTOT    (NWQ+NWO+NWF1+NWF2)   // 8388608

typedef __attribute__((ext_vector_type(8))) short s16x8;
typedef __attribute__((ext_vector_type(4))) float f32x4;
#define MFMA(a,b,c) __builtin_amdgcn_mfma_f32_16x16x32_bf16(a,b,c,0,0,0)

// split fp32 -> bf16 hi (truncate) + bf16 lo (truncated residual); a ~= hi + lo
__device__ __forceinline__ void split_bf16(float a, short &h, short &l) {
  unsigned u = __float_as_uint(a);
  h = (short)(u >> 16);
  float ah = __uint_as_float(u & 0xffff0000u);
  float al = a - ah;
  l = (short)(__float_as_uint(al) >> 16);
}

// exact (non-FMA-contracted) squared distance, matching XLA's mul+add order
__device__ __forceinline__ float d2_3(float ax, float ay, float az,
                                      float bx, float by, float bz) {
#pragma clang fp contract(off)
  float dx = ax - bx, dy = ay - by, dz = az - bz;
  float dx2 = dx * dx, dy2 = dy * dy, dz2 = dz * dz;
  return (dx2 + dy2) + dz2;
}

__device__ __forceinline__ float gelu_f(float v) {
  return 0.5f * v * (1.0f + erff(v * 0.70710678118654752440f));
}

// ---------------- one-time weight split ----------------
__global__ __launch_bounds__(256) void splitw_kernel(
    const float* __restrict__ qkv_w, const float* __restrict__ out_w,
    const float* __restrict__ ff1_w, const float* __restrict__ ff2_w,
    short* __restrict__ wh, short* __restrict__ wl) {
  int i = blockIdx.x * 256 + threadIdx.x;
  const float* src; int off;
  if (i < WOOFF)        { src = qkv_w; off = i; }
  else if (i < WF1OFF)  { src = out_w; off = i - WOOFF; }
  else if (i < WF2OFF)  { src = ff1_w; off = i - WF1OFF; }
  else                  { src = ff2_w; off = i - WF2OFF; }
  float v = src[off];
  short h, l; split_bf16(v, h, l);
  wh[i] = h; wl[i] = l;
}

// ---------------- FPS v2: one block per (b, ti), 1 barrier/iter ----------------
__global__ __launch_bounds__(256) void fps_kernel(const float* __restrict__ xyzs,
                                                  float* __restrict__ anchor) {
  __shared__ float sx[NN], sy[NN], sz[NN];
  __shared__ unsigned long long skey[2][4];
  int blk = blockIdx.x;
  int b = blk / TO, ti = blk - b * TO;
  const float* src = xyzs + ((size_t)(b * TT + 2 * ti)) * NN * 3;
  int tid = threadIdx.x;
  float dist[16], px[16], py[16], pz[16];
#pragma unroll
  for (int s = 0; s < 16; ++s) {
    int p = tid + s * 256;
    px[s] = src[p * 3 + 0]; py[s] = src[p * 3 + 1]; pz[s] = src[p * 3 + 2];
    sx[p] = px[s]; sy[p] = py[s]; sz[p] = pz[s];
    dist[s] = 1e10f;
  }
  __syncthreads();
  float lx = sx[0], ly = sy[0], lz = sz[0];
  float* aout = anchor + (size_t)blk * MM * 3;
  if (tid == 0) { aout[0] = lx; aout[1] = ly; aout[2] = lz; }
  for (int j = 1; j < MM; ++j) {
    unsigned long long best = 0;
#pragma unroll
    for (int s = 0; s < 16; ++s) {
      float d2 = d2_3(px[s], py[s], pz[s], lx, ly, lz);
      float dn = fminf(dist[s], d2);
      dist[s] = dn;
      unsigned long long key = ((unsigned long long)__float_as_uint(dn) << 12)
                               | (unsigned)(4095 - (tid + s * 256));
      best = key > best ? key : best;
    }
#pragma unroll
    for (int m = 1; m < 64; m <<= 1) {
      unsigned long long o = __shfl_xor(best, m, 64);
      best = o > best ? o : best;
    }
    if ((tid & 63) == 0) skey[j & 1][tid >> 6] = best;
    __syncthreads();
    unsigned long long b0 = skey[j & 1][0], b1 = skey[j & 1][1];
    unsigned long long b2 = skey[j & 1][2], b3 = skey[j & 1][3];
    unsigned long long bb = b0 > b1 ? b0 : b1;
    unsigned long long cc = b2 > b3 ? b2 : b3;
    bb = bb > cc ? bb : cc;
    int bi = 4095 - (int)(bb & 0xFFFull);
    lx = sx[bi]; ly = sy[bi]; lz = sz[bi];
    if (tid == 0) { aout[j * 3 + 0] = lx; aout[j * 3 + 1] = ly; aout[j * 3 + 2] = lz; }
  }
}

// ---------------- ball query + p4dconv v2: 4 anchors / 256-thr block, chunked scan,
// one wave per anchor, no barriers (per-wave LDS slices) ----------------
__global__ __launch_bounds__(256) void ballconv_kernel(
    const float* __restrict__ xyzs, const float* __restrict__ oldf,
    const float* __restrict__ anchor,
    const float* __restrict__ wdw, const float* __restrict__ wfw,
    float* __restrict__ dout) {
  __shared__ int   sidx[4][32];
  __shared__ float sdisp[4][32][4];
  __shared__ float sfeat[4][32][2];
  int g = blockIdx.x;                       // group of 4 anchors
  int b = g / (TO * 32);
  int rem = g - b * (TO * 32);
  int ti = rem >> 5;
  int mg = rem & 31;
  int tid = threadIdx.x, lane = tid & 63, w = tid >> 6;
  int blk = b * (TO * MM) + ti * MM + mg * 4 + w;   // this wave's anchor
  const float* ap = anchor + (size_t)blk * 3;
  float ax = ap[0], ay = ap[1], az = ap[2];
  int d0 = lane * 8;
  float4 wd[8]; float2 wf[8];
#pragma unroll
  for (int jd = 0; jd < 8; ++jd) {
    wd[jd] = *(const float4*)(wdw + (d0 + jd) * 4);
    wf[jd] = *(const float2*)(wfw + (d0 + jd) * 2);
  }
  float fmx[8];
#pragma unroll
  for (int jd = 0; jd < 8; ++jd) fmx[jd] = -INFINITY;

  for (int o = -1; o <= 1; ++o) {
    int tp = 1 + 2 * ti + o;
    int orig = (tp == 0) ? 0 : tp - 1;
    const float* nx = xyzs + ((size_t)(b * TT + orig)) * NN * 3;
    const float* nf = oldf + ((size_t)(b * TT + orig)) * 2 * NN;
    int cnt = 0;
    // chunked scan: 8 batches (512 points) per chunk; loads fully pipelined within chunk
    for (int base0 = 0; base0 < NN && cnt < 32; base0 += 512) {
      unsigned long long masks[8];
#pragma unroll
      for (int u = 0; u < 8; ++u) {
        int p = base0 + u * 64 + lane;
        float d2 = d2_3(ax, ay, az, nx[p * 3], nx[p * 3 + 1], nx[p * 3 + 2]);
        masks[u] = __ballot(d2 < 0.09f);
      }
#pragma unroll
      for (int u = 0; u < 8; ++u) {
        unsigned long long mask = masks[u];
        int pos = __popcll(mask & ((1ull << lane) - 1ull));
        bool in = (mask >> lane) & 1ull;
        if (in && (cnt + pos) < 32) sidx[w][cnt + pos] = base0 + u * 64 + lane;
        cnt += __popcll(mask);
      }
    }
    int used = cnt < 32 ? cnt : 32;
    if (lane < 32 && lane >= used) sidx[w][lane] = (used > 0) ? sidx[w][0] : 0;
    if (lane < 32) {
      int p = sidx[w][lane];
      sdisp[w][lane][0] = nx[p * 3 + 0] - ax;
      sdisp[w][lane][1] = nx[p * 3 + 1] - ay;
      sdisp[w][lane][2] = nx[p * 3 + 2] - az;
      sdisp[w][lane][3] = (float)o;
      sfeat[w][lane][0] = nf[p];
      sfeat[w][lane][1] = nf[NN + p];
    }
    // same-wave LDS RAW ordering is compiler-handled; no barrier needed (per-wave slices)
    for (int k = 0; k < 32; ++k) {
      float p0 = sdisp[w][k][0], p1 = sdisp[w][k][1], p2 = sdisp[w][k][2], p3 = sdisp[w][k][3];
      float f0 = sfeat[w][k][0], f1 = sfeat[w][k][1];
#pragma unroll
      for (int jd = 0; jd < 8; ++jd) {
        float de = wd[jd].x * p0 + wd[jd].y * p1 + wd[jd].z * p2 + wd[jd].w * p3;
        float fe = wf[jd].x * f0 + wf[jd].y * f1;
        fmx[jd] = fmaxf(fmx[jd], fe * de);
      }
    }
  }
  float* fout = dout + OUT_FEATS + (size_t)blk * DM + d0;
#pragma unroll
  for (int jd = 0; jd < 8; jd += 4)
    *(float4*)(fout + jd) = make_float4(fmx[jd], fmx[jd + 1], fmx[jd + 2], fmx[jd + 3]);
}

// ---------------- pos/contrastive embed + x = relu(pos + features) ----------------
__global__ __launch_bounds__(256) void posx_kernel(
    const float* __restrict__ anchor,
    const float* __restrict__ pw, const float* __restrict__ pb,
    const float* __restrict__ cw, const float* __restrict__ cb,
    float* __restrict__ dout, float* __restrict__ x) {
  int idx = blockIdx.x * 256 + threadIdx.x;
  int bl = idx >> 9, d = idx & 511;
  int ti = (bl % LL) / MM;
  const float* ap = anchor + (size_t)bl * 3;
  float c0 = ap[0], c1 = ap[1], c2 = ap[2], c3 = (float)(ti + 1);
  float4 pwv = *(const float4*)(pw + d * 4);
  float4 cwv = *(const float4*)(cw + d * 4);
  float pos = pwv.x * c0 + pwv.y * c1 + pwv.z * c2 + pwv.w * c3 + pb[d];
  float con = cwv.x * c0 + cwv.y * c1 + cwv.z * c2 + cwv.w * c3 + cb[d];
  dout[OUT_CONTR + (size_t)idx] = con;
  float v = pos + dout[OUT_FEATS + (size_t)idx];
  x[idx] = v > 0.0f ? v : 0.0f;
}

// ---------------- LayerNorm -> split bf16 hi/lo: 4 rows / 256-thr block ----------------
__global__ __launch_bounds__(256) void ln_split_kernel(
    const float* __restrict__ x, const float* __restrict__ gs,
    const float* __restrict__ gb, short* __restrict__ oh, short* __restrict__ ol) {
  int row = blockIdx.x * 4 + (threadIdx.x >> 6), lane = threadIdx.x & 63;
  const float* xr = x + (size_t)row * DM + lane * 8;
  float4 v0 = *(const float4*)xr;
  float4 v1 = *(const float4*)(xr + 4);
  float v[8] = {v0.x, v0.y, v0.z, v0.w, v1.x, v1.y, v1.z, v1.w};
  float s = 0.f;
#pragma unroll
  for (int j = 0; j < 8; ++j) s += v[j];
  for (int m = 1; m < 64; m <<= 1) s += __shfl_xor(s, m, 64);
  float mu = s * (1.0f / DM);
  float d[8], ss = 0.f;
#pragma unroll
  for (int j = 0; j < 8; ++j) { d[j] = v[j] - mu; ss += d[j] * d[j]; }
  for (int m = 1; m < 64; m <<= 1) ss += __shfl_xor(ss, m, 64);
  float rs = 1.0f / sqrtf(ss * (1.0f / DM) + 1e-5f);
  const float* gsr = gs + lane * 8;
  const float* gbr = gb + lane * 8;
  s16x8 hv, lv;
#pragma unroll
  for (int j = 0; j < 8; ++j) {
    float f = d[j] * rs * gsr[j] + gbr[j];
    short h, l; split_bf16(f, h, l);
    hv[j] = h; lv[j] = l;
  }
  *(s16x8*)(oh + (size_t)row * DM + lane * 8) = hv;
  *(s16x8*)(ol + (size_t)row * DM + lane * 8) = lv;
}

// ---------------- LayerNorm fp32 out (head path) ----------------
__global__ __launch_bounds__(64) void ln_kernel(
    const float* __restrict__ x, const float* __restrict__ gs,
    const float* __restrict__ gb, float* __restrict__ out) {
  int row = blockIdx.x, lane = threadIdx.x;
  const float* xr = x + (size_t)row * DM + lane * 8;
  float4 v0 = *(const float4*)xr;
  float4 v1 = *(const float4*)(xr + 4);
  float v[8] = {v0.x, v0.y, v0.z, v0.w, v1.x, v1.y, v1.z, v1.w};
  float s = 0.f;
#pragma unroll
  for (int j = 0; j < 8; ++j) s += v[j];
  for (int m = 1; m < 64; m <<= 1) s += __shfl_xor(s, m, 64);
  float mu = s * (1.0f / DM);
  float d[8], ss = 0.f;
#pragma unroll
  for (int j = 0; j < 8; ++j) { d[j] = v[j] - mu; ss += d[j] * d[j]; }
  for (int m = 1; m < 64; m <<= 1) ss += __shfl_xor(ss, m, 64);
  float rs = 1.0f / sqrtf(ss * (1.0f / DM) + 1e-5f);
  const float* gsr = gs + lane * 8;
  const float* gbr = gb + lane * 8;
  float* orow = out + (size_t)row * DM + lane * 8;
  float r[8];
#pragma unroll
  for (int j = 0; j < 8; ++j) r[j] = d[j] * rs * gsr[j] + gbr[j];
  *(float4*)orow       = make_float4(r[0], r[1], r[2], r[3]);
  *(float4*)(orow + 4) = make_float4(r[4], r[5], r[6], r[7]);
}

// ---------------- split-bf16 MFMA GEMM 128x128 (pre-split A and W) ----------------
// EPI: 1 = qkv (q scaled by 0.125, q,k -> Ch/Cl stride 1024; v -> vT transposed),
//      2 = bias+gelu+split-out, 3 = bias+residual fp32 out
template <int EPI>
__global__ __launch_bounds__(256) void mgemm_kernel(
    const short* __restrict__ Ah, const short* __restrict__ Al,
    const short* __restrict__ Wh, const short* __restrict__ Wl,
    const float* __restrict__ bias, const float* __restrict__ res,
    float* __restrict__ Cf, short* __restrict__ Ch, short* __restrict__ Cl,
    short* __restrict__ vTh, short* __restrict__ vTl,
    int M, int N, int K) {
  __shared__ short As[2][128 * 40];   // [hi/lo][row][k(32)+pad8]
  __shared__ short Ws[2][128 * 40];
  int tid = threadIdx.x;
  int lane = tid & 63, w = tid >> 6;
  int wr = w >> 1, wc = w & 1;
  int row0 = blockIdx.y * 128, col0 = blockIdx.x * 128;
  int srow = tid >> 1, skc = (tid & 1) * 16;
  const short* Ahp = Ah + (size_t)(row0 + srow) * K + skc;
  const short* Alp = Al + (size_t)(row0 + srow) * K + skc;
  const short* Whp = Wh + (size_t)(col0 + srow) * K + skc;
  const short* Wlp = Wl + (size_t)(col0 + srow) * K + skc;
  int fr = lane & 15, fk = (lane >> 4) * 8;
  f32x4 acc[16];
#pragma unroll
  for (int i = 0; i < 16; ++i) acc[i] = (f32x4){0.f, 0.f, 0.f, 0.f};
  s16x8 rA0 = *(const s16x8*)(Ahp);
  s16x8 rA1 = *(const s16x8*)(Ahp + 8);
  s16x8 rA2 = *(const s16x8*)(Alp);
  s16x8 rA3 = *(const s16x8*)(Alp + 8);
  s16x8 rW0 = *(const s16x8*)(Whp);
  s16x8 rW1 = *(const s16x8*)(Whp + 8);
  s16x8 rW2 = *(const s16x8*)(Wlp);
  s16x8 rW3 = *(const s16x8*)(Wlp + 8);
  for (int ks = 0; ks < K; ks += 32) {
    __syncthreads();
    *(s16x8*)&As[0][srow * 40 + skc]     = rA0;
    *(s16x8*)&As[0][srow * 40 + skc + 8] = rA1;
    *(s16x8*)&As[1][srow * 40 + skc]     = rA2;
    *(s16x8*)&As[1][srow * 40 + skc + 8] = rA3;
    *(s16x8*)&Ws[0][srow * 40 + skc]     = rW0;
    *(s16x8*)&Ws[0][srow * 40 + skc + 8] = rW1;
    *(s16x8*)&Ws[1][srow * 40 + skc]     = rW2;
    *(s16x8*)&Ws[1][srow * 40 + skc + 8] = rW3;
    __syncthreads();
    if (ks + 32 < K) {
      rA0 = *(const s16x8*)(Ahp + ks + 32);
      rA1 = *(const s16x8*)(Ahp + ks + 40);
      rA2 = *(const s16x8*)(Alp + ks + 32);
      rA3 = *(const s16x8*)(Alp + ks + 40);
      rW0 = *(const s16x8*)(Whp + ks + 32);
      rW1 = *(const s16x8*)(Whp + ks + 40);
      rW2 = *(const s16x8*)(Wlp + ks + 32);
      rW3 = *(const s16x8*)(Wlp + ks + 40);
    }
    s16x8 bh_[4], bl_[4];
#pragma unroll
    for (int t = 0; t < 4; ++t) {
      bh_[t] = *(const s16x8*)&Ws[0][(wc * 64 + t * 16 + fr) * 40 + fk];
      bl_[t] = *(const s16x8*)&Ws[1][(wc * 64 + t * 16 + fr) * 40 + fk];
    }
#pragma unroll
    for (int a = 0; a < 4; ++a) {
      s16x8 ah_ = *(const s16x8*)&As[0][(wr * 64 + a * 16 + fr) * 40 + fk];
      s16x8 al_ = *(const s16x8*)&As[1][(wr * 64 + a * 16 + fr) * 40 + fk];
#pragma unroll
      for (int t = 0; t < 4; ++t) {
        f32x4 c = acc[a * 4 + t];
        c = MFMA(ah_, bh_[t], c);
        c = MFMA(ah_, bl_[t], c);
        c = MFMA(al_, bh_[t], c);
        acc[a * 4 + t] = c;
      }
    }
  }
  int fq = lane >> 4;
  if (EPI == 1) {
    int bidx = row0 / LL;
    int j0 = row0 - bidx * LL + wr * 64;
    float qscale = (col0 < 512) ? 0.125f : 1.0f;  // exact pow2: commutes with split
#pragma unroll
    for (int a = 0; a < 4; ++a) {
#pragma unroll
      for (int t = 0; t < 4; ++t) {
        int c = col0 + wc * 64 + t * 16 + fr;
        f32x4 v = acc[a * 4 + t];
        if (col0 < 1024) {  // q,k -> row-major stride 1024
#pragma unroll
          for (int r = 0; r < 4; ++r) {
            int row = row0 + wr * 64 + a * 16 + fq * 4 + r;
            size_t off = (size_t)row * 1024 + c;
            short h, l; split_bf16(v[r] * qscale, h, l);
            Ch[off] = h; Cl[off] = l;
          }
        } else {            // v -> transposed [(b*8+h)*64+d][LL], 4 rows packed per store
          int vcol = c - 1024;
          size_t vidx = ((size_t)(bidx * 8 + (vcol >> 6)) * 64 + (vcol & 63)) * LL
                        + j0 + a * 16 + fq * 4;
          short4 hv, lv;
          short h, l;
          split_bf16(v[0], h, l); hv.x = h; lv.x = l;
          split_bf16(v[1], h, l); hv.y = h; lv.y = l;
          split_bf16(v[2], h, l); hv.z = h; lv.z = l;
          split_bf16(v[3], h, l); hv.w = h; lv.w = l;
          *(short4*)(vTh + vidx) = hv;
          *(short4*)(vTl + vidx) = lv;
        }
      }
    }
  } else {
#pragma unroll
    for (int a = 0; a < 4; ++a) {
#pragma unroll
      for (int t = 0; t < 4; ++t) {
#pragma unroll
        for (int r = 0; r < 4; ++r) {
          int row = row0 + wr * 64 + a * 16 + fq * 4 + r;
          int c   = col0 + wc * 64 + t * 16 + fr;
          size_t off = (size_t)row * N + c;
          float v = acc[a * 4 + t][r] + bias[c];
          if (EPI == 2) {
            v = gelu_f(v);
            short h, l; split_bf16(v, h, l);
            Ch[off] = h; Cl[off] = l;
          } else {
            Cf[off] = v + res[off];
          }
        }
      }
    }
  }
}

// ---------------- split-bf16 MFMA flash attention v7 ----------------
// 128 q-rows, 8 waves, XCD-aware grid; __expf; l-accum on matrix pipe (B=ones).
__global__ __launch_bounds__(512) void mattn_kernel(
    const short* __restrict__ qkh, const short* __restrict__ qkl,
    const short* __restrict__ vTh, const short* __restrict__ vTl,
    short* __restrict__ oh, short* __restrict__ ol) {
  __shared__ short Ks[2][64 * 72];
  __shared__ short Vs[2][64 * 72];
  __shared__ short Ps[2][128 * 72];
  int n = blockIdx.x;
  int bh = n & 31, it = n >> 5;
  int b = bh >> 3, h = bh & 7;
  int tid = threadIdx.x, lane = tid & 63, w = tid >> 6;  // w in 0..7
  int fr = lane & 15, fq = lane >> 4, fk = fq * 8;
  size_t rowbase = (size_t)b * LL;
  s16x8 qfh[2], qfl[2];
  {
    size_t qoff = (size_t)(rowbase + it * 128 + w * 16 + fr) * 1024 + h * DH;
    qfh[0] = *(const s16x8*)(qkh + qoff + fk);
    qfh[1] = *(const s16x8*)(qkh + qoff + 32 + fk);
    qfl[0] = *(const s16x8*)(qkl + qoff + fk);
    qfl[1] = *(const s16x8*)(qkl + qoff + 32 + fk);
  }
  s16x8 ones;
#pragma unroll
  for (int j = 0; j < 8; ++j) ones[j] = (short)0x3F80;   // bf16 1.0
  const short* vbh = vTh + (size_t)(b * 8 + h) * 64 * LL;
  const short* vbl = vTl + (size_t)(b * 8 + h) * 64 * LL;
  float m_i[4];
  f32x4 oac[4], lsacc;
#pragma unroll
  for (int r = 0; r < 4; ++r) m_i[r] = -INFINITY;
  lsacc = (f32x4){0.f, 0.f, 0.f, 0.f};
#pragma unroll
  for (int t = 0; t < 4; ++t) oac[t] = (f32x4){0.f, 0.f, 0.f, 0.f};
  int sr = tid >> 3, sc = (tid & 7) * 8;   // staging: row 0..63, col 0,8,..,56
  for (int jt = 0; jt < LL / 64; ++jt) {
    size_t kbase = (size_t)(rowbase + jt * 64 + sr) * 1024 + 512 + h * DH + sc;
    s16x8 k0 = *(const s16x8*)(qkh + kbase);
    s16x8 k1 = *(const s16x8*)(qkl + kbase);
    size_t vgb = (size_t)sr * LL + jt * 64 + sc;
    s16x8 v0 = *(const s16x8*)(vbh + vgb);
    s16x8 v1 = *(const s16x8*)(vbl + vgb);
    __syncthreads();   // prev iter's K/V LDS reads done
    *(s16x8*)&Ks[0][sr * 72 + sc] = k0;
    *(s16x8*)&Ks[1][sr * 72 + sc] = k1;
    *(s16x8*)&Vs[0][sr * 72 + sc] = v0;
    *(s16x8*)&Vs[1][sr * 72 + sc] = v1;
    __syncthreads();
    // QK^T (q pre-scaled by 0.125 at the qkv epilogue)
    f32x4 s[4];
#pragma unroll
    for (int t = 0; t < 4; ++t) s[t] = (f32x4){0.f, 0.f, 0.f, 0.f};
#pragma unroll
    for (int ks = 0; ks < 2; ++ks) {
#pragma unroll
      for (int t = 0; t < 4; ++t) {
        s16x8 kh_ = *(const s16x8*)&Ks[0][(t * 16 + fr) * 72 + ks * 32 + fk];
        s16x8 kl_ = *(const s16x8*)&Ks[1][(t * 16 + fr) * 72 + ks * 32 + fk];
        s[t] = MFMA(qfh[ks], kh_, s[t]);
        s[t] = MFMA(qfh[ks], kl_, s[t]);
        s[t] = MFMA(qfl[ks], kh_, s[t]);
      }
    }
    // online softmax (max via shuffles; sums accumulated on the matrix pipe below)
#pragma unroll
    for (int r = 0; r < 4; ++r) {
      float s0 = s[0][r], s1 = s[1][r], s2 = s[2][r], s3 = s[3][r];
      float mr = fmaxf(fmaxf(s0, s1), fmaxf(s2, s3));
      mr = fmaxf(mr, __shfl_xor(mr, 1, 64));
      mr = fmaxf(mr, __shfl_xor(mr, 2, 64));
      mr = fmaxf(mr, __shfl_xor(mr, 4, 64));
      mr = fmaxf(mr, __shfl_xor(mr, 8, 64));
      float mn = fmaxf(m_i[r], mr);
      float al = __expf(m_i[r] - mn);
      float p0 = __expf(s0 - mn), p1 = __expf(s1 - mn);
      float p2 = __expf(s2 - mn), p3 = __expf(s3 - mn);
      m_i[r] = mn;
      lsacc[r] *= al;
      oac[0][r] *= al; oac[1][r] *= al; oac[2][r] *= al; oac[3][r] *= al;
      int prow = (w * 16 + fq * 4 + r) * 72;
      short hh_, ll_;
      split_bf16(p0, hh_, ll_); Ps[0][prow + fr]      = hh_; Ps[1][prow + fr]      = ll_;
      split_bf16(p1, hh_, ll_); Ps[0][prow + 16 + fr] = hh_; Ps[1][prow + 16 + fr] = ll_;
      split_bf16(p2, hh_, ll_); Ps[0][prow + 32 + fr] = hh_; Ps[1][prow + 32 + fr] = ll_;
      split_bf16(p3, hh_, ll_); Ps[0][prow + 48 + fr] = hh_; Ps[1][prow + 48 + fr] = ll_;
    }
    // PV + row-sum (Ps rows are wave-exclusive: same-wave DS ordering, no barrier)
#pragma unroll
    for (int ks = 0; ks < 2; ++ks) {
      s16x8 ph_ = *(const s16x8*)&Ps[0][(w * 16 + fr) * 72 + ks * 32 + fk];
      s16x8 pl_ = *(const s16x8*)&Ps[1][(w * 16 + fr) * 72 + ks * 32 + fk];
#pragma unroll
      for (int t = 0; t < 4; ++t) {
        s16x8 vh_ = *(const s16x8*)&Vs[0][(t * 16 + fr) * 72 + ks * 32 + fk];
        s16x8 vl_ = *(const s16x8*)&Vs[1][(t * 16 + fr) * 72 + ks * 32 + fk];
        oac[t] = MFMA(ph_, vh_, oac[t]);
        oac[t] = MFMA(ph_, vl_, oac[t]);
        oac[t] = MFMA(pl_, vh_, oac[t]);
      }
      lsacc = MFMA(ph_, ones, lsacc);
      lsacc = MFMA(pl_, ones, lsacc);
    }
  }
#pragma unroll
  for (int r = 0; r < 4; ++r) {
    float inv = 1.0f / lsacc[r];
    size_t row = rowbase + it * 128 + w * 16 + fq * 4 + r;
#pragma unroll
    for (int t = 0; t < 4; ++t) {
      float v = oac[t][r] * inv;
      short hh_, ll_; split_bf16(v, hh_, ll_);
      size_t off = row * DM + h * DH + t * 16 + fr;
      oh[off] = hh_; ol[off] = ll_;
    }
  }
}

// ---------------- max-pool over sequence (two stage) ----------------
__global__ __launch_bounds__(256) void poolmax1_kernel(const float* __restrict__ x,
                                                       float* __restrict__ partial) {
  int ch = blockIdx.x, b = blockIdx.y, tid = threadIdx.x;
  const float* p = x + ((size_t)b * LL + ch * 128) * DM;
  float m0 = -INFINITY, m1 = -INFINITY;
#pragma unroll 4
  for (int l = 0; l < 128; ++l) {
    m0 = fmaxf(m0, p[(size_t)l * DM + tid]);
    m1 = fmaxf(m1, p[(size_t)l * DM + tid + 256]);
  }
  partial[(size_t)(b * TO + ch) * DM + tid] = m0;
  partial[(size_t)(b * TO + ch) * DM + tid + 256] = m1;
}

__global__ __launch_bounds__(256) void poolmax2_kernel(const float* __restrict__ partial,
                                                       float* __restrict__ pooled) {
  int idx = blockIdx.x * 256 + threadIdx.x;
  int b = idx >> 9, d = idx & 511;
  float m = -INFINITY;
#pragma unroll
  for (int c = 0; c < TO; ++c) m = fmaxf(m, partial[(size_t)(b * TO + c) * DM + d]);
  pooled[idx] = m;
}

// ---------------- head MLP ----------------
__global__ __launch_bounds__(256) void head1_kernel(const float* __restrict__ lnp,
                                                    const float* __restrict__ w,
                                                    const float* __restrict__ bb,
                                                    float* __restrict__ hid) {
  int idx = blockIdx.x * 256 + threadIdx.x;
  int b = idx >> 10, n = idx & 1023;
  const float* xr = lnp + (size_t)b * DM;
  const float* wr = w + (size_t)n * DM;
  float s = 0.f;
  for (int k = 0; k < DM; k += 4) {
    float4 xv = *(const float4*)(xr + k);
    float4 wv = *(const float4*)(wr + k);
    s += xv.x * wv.x + xv.y * wv.y + xv.z * wv.z + xv.w * wv.w;
  }
  hid[idx] = gelu_f(s + bb[n]);
}

__global__ __launch_bounds__(128) void head2_kernel(const float* __restrict__ hid,
                                                    const float* __restrict__ w,
                                                    const float* __restrict__ bb,
                                                    float* __restrict__ dout) {
  int t = threadIdx.x;
  if (t < BN_ * NC) {
    int b = t / NC, n = t - b * NC;
    const float* xr = hid + (size_t)b * MLPD;
    const float* wr = w + (size_t)n * MLPD;
    float s = 0.f;
    for (int k = 0; k < MLPD; k += 4) {
      float4 xv = *(const float4*)(xr + k);
      float4 wv = *(const float4*)(wr + k);
      s += xv.x * wv.x + xv.y * wv.y + xv.z * wv.z + xv.w * wv.w;
    }
    dout[OUT_LOGITS + t] = s + bb[n];
  }
}

// ---------------- launch ----------------
extern "C" void kernel_launch(void* const* d_in, const int* in_sizes, int n_in,
                              void* d_out, int out_size, void* d_ws, size_t ws_size,
                              hipStream_t stream) {
  (void)in_sizes; (void)n_in; (void)out_size; (void)ws_size;
  const float* xyzs     = (const float*)d_in[0];
  const float* oldf     = (const float*)d_in[1];
  const float* conv_d_w = (const float*)d_in[2];
  const float* conv_f_w = (const float*)d_in[3];
  const float* pos_w    = (const float*)d_in[4];
  const float* pos_b    = (const float*)d_in[5];
  const float* contr_w  = (const float*)d_in[6];
  const float* contr_b  = (const float*)d_in[7];
  const float* ln1_s    = (const float*)d_in[8];
  const float* ln1_b    = (const float*)d_in[9];
  const float* qkv_w    = (const float*)d_in[10];
  const float* out_w    = (const float*)d_in[11];
  const float* out_b    = (const float*)d_in[12];
  const float* ln2_s    = (const float*)d_in[13];
  const float* ln2_b    = (const float*)d_in[14];
  const float* ff1_w    = (const float*)d_in[15];
  const float* ff1_b    = (const float*)d_in[16];
  const float* ff2_w    = (const float*)d_in[17];
  const float* ff2_b    = (const float*)d_in[18];
  const float* hl_s     = (const float*)d_in[19];
  const float* hl_b     = (const float*)d_in[20];
  const float* h1_w     = (const float*)d_in[21];
  const float* h1_b     = (const float*)d_in[22];
  const float* h2_w     = (const float*)d_in[23];
  const float* h2_b     = (const float*)d_in[24];
  float* dout = (float*)d_out;
  char* base = (char*)d_ws;
  auto alloc = [&](size_t bytes) { char* p = base; base += (bytes + 255) & ~(size_t)255; return p; };

  float* anchor = (float*)alloc((size_t)BN_ * TO * MM * 3 * 4);
  float* x      = (float*)alloc((size_t)BL * DM * 4);
  short* qkvh   = (short*)alloc((size_t)BL * 1024 * 2);   // q|k packed, stride 1024
  short* qkvl   = (short*)alloc((size_t)BL * 1024 * 2);
  short* vTh    = (short*)alloc((size_t)BN_ * NH * DH * LL * 2);
  short* vTl    = (short*)alloc((size_t)BN_ * NH * DH * LL * 2);
  short* atnh   = (short*)alloc((size_t)BL * DM * 2);
  short* atnl   = (short*)alloc((size_t)BL * DM * 2);
  short* hh     = (short*)alloc((size_t)BL * DM * 2);
  short* hl     = (short*)alloc((size_t)BL * DM * 2);
  short* wsh    = (short*)alloc((size_t)WTOT * 2);
  short* wsl    = (short*)alloc((size_t)WTOT * 2);
  float* partial= (float*)alloc((size_t)BN_ * TO * DM * 4);
  float* pooled = (float*)alloc((size_t)BN_ * DM * 4);
  float* lnp    = (float*)alloc((size_t)BN_ * DM * 4);
  float* hid    = (float*)alloc((size_t)BN_ * MLPD * 4);
  short* fh = qkvh;  // FF hidden aliases qkv (BL*1024 shorts, consumed by then)
  short* fl = qkvl;

  splitw_kernel<<<WTOT / 256, 256, 0, stream>>>(qkv_w, out_w, ff1_w, ff2_w, wsh, wsl);
  fps_kernel<<<BN_ * TO, 256, 0, stream>>>(xyzs, anchor);
  ballconv_kernel<<<BN_ * TO * MM / 4, 256, 0, stream>>>(xyzs, oldf, anchor, conv_d_w, conv_f_w, dout);
  posx_kernel<<<(BL * DM) / 256, 256, 0, stream>>>(anchor, pos_w, pos_b, contr_w, contr_b, dout, x);

  for (int l = 0; l < 4; ++l) {
    ln_split_kernel<<<BL / 4, 256, 0, stream>>>(x, ln1_s + l * DM, ln1_b + l * DM, hh, hl);
    mgemm_kernel<1><<<dim3(1536 / 128, BL / 128), 256, 0, stream>>>(
        hh, hl, wsh + WQOFF + (size_t)l * 786432, wsl + WQOFF + (size_t)l * 786432,
        nullptr, nullptr, nullptr, qkvh, qkvl, vTh, vTl, BL, 1536, DM);
    mattn_kernel<<<dim3((LL / 128) * 32), 512, 0, stream>>>(qkvh, qkvl, vTh, vTl, atnh, atnl);
    mgemm_kernel<3><<<dim3(DM / 128, BL / 128), 256, 0, stream>>>(
        atnh, atnl, wsh + WOOFF + (size_t)l * 262144, wsl + WOOFF + (size_t)l * 262144,
        out_b + l * DM, x, x, nullptr, nullptr, nullptr, nullptr, BL, DM, DM);
    ln_split_kernel<<<BL / 4, 256, 0, stream>>>(x, ln2_s + l * DM, ln2_b + l * DM, hh, hl);
    mgemm_kernel<2><<<dim3(MLPD / 128, BL / 128), 256, 0, stream>>>(
        hh, hl, wsh + WF1OFF + (size_t)l * 524288, wsl + WF1OFF + (size_t)l * 524288,
        ff1_b + l * MLPD, nullptr, nullptr, fh, fl, nullptr, nullptr, BL, MLPD, DM);
    mgemm_kernel<3><<<dim3(DM / 128, BL / 128), 256, 0, stream>>>(
        fh, fl, wsh + WF2OFF + (size_t)l * 524288, wsl + WF2OFF + (size_t)l * 524288,
        ff2_b + l * DM, x, x, nullptr, nullptr, nullptr, nullptr, BL, DM, MLPD);
  }

  poolmax1_kernel<<<dim3(TO, BN_), 256, 0, stream>>>(x, partial);
  poolmax2_kernel<<<(BN_ * DM) / 256, 256, 0, stream>>>(partial, pooled);
  ln_kernel<<<BN_, 64, 0, stream>>>(pooled, hl_s, hl_b, lnp);
  head1_kernel<<<(BN_ * MLPD) / 256, 256, 0, stream>>>(lnp, h1_w, h1_b, hid);
  head2_kernel<<<1, 128, 0, stream>>>(hid, h2_w, h2_b, dout);
}